// Round 13
// baseline (399.980 us; speedup 1.0000x reference)
//
#include <hip/hip_runtime.h>
#include <stdint.h>

typedef __attribute__((ext_vector_type(4))) float f32x4;
typedef __attribute__((ext_vector_type(8))) short bf16x8;
typedef __attribute__((ext_vector_type(4))) short s16x4;
typedef __attribute__((ext_vector_type(4))) float fp32x4;

#define QSCALE 0.18033688f   // 0.125 * log2(e): scores exit QK^T in log2 domain

__device__ __forceinline__ short f2bf(float f) {
    union { float f; unsigned u; } v; v.f = f;
    unsigned u = v.u;
    unsigned r = u + 0x7fffu + ((u >> 16) & 1u);
    return (short)(r >> 16);
}
// packed bf16 convert (RNE), lo = a, hi = b
__device__ __forceinline__ unsigned cvtpk(float a, float b) {
    unsigned r;
    asm("v_cvt_pk_bf16_f32 %0, %1, %2" : "=v"(r) : "v"(a), "v"(b));
    return r;
}

// async global->LDS, 16B per lane. dest = wave-uniform base + lane*16.
__device__ __forceinline__ void gld_lds16(const void* g, void* l) {
    __builtin_amdgcn_global_load_lds(
        (const __attribute__((address_space(1))) unsigned int*)(uintptr_t)g,
        (__attribute__((address_space(3))) unsigned int*)(uintptr_t)l,
        16, 0, 0);
}

// ---------------- fused prep: all casts + RoPE table in ONE launch --------
__global__ __launch_bounds__(256) void prep_kernel(const float* __restrict__ x,
                                                   const float* __restrict__ wq,
                                                   const float* __restrict__ wo,
                                                   short* __restrict__ xb,
                                                   short* __restrict__ wqb,
                                                   short* __restrict__ wob,
                                                   float* __restrict__ tab) {
    int bid = blockIdx.x, tid = threadIdx.x;
    if (bid < 6144) {
        const float* in; short* out; int base;
        if (bid < 4096)      { in = x;  out = xb;  base = bid; }
        else if (bid < 5632) { in = wq; out = wqb; base = bid - 4096; }
        else                 { in = wo; out = wob; base = bid - 5632; }
        int idx = (base * 256 + tid) * 8;
        fp32x4 a = *(const fp32x4*)&in[idx];
        fp32x4 b = *(const fp32x4*)&in[idx + 4];
        union { unsigned w[4]; bf16x8 v; } u;
        u.w[0] = cvtpk(a[0], a[1]); u.w[1] = cvtpk(a[2], a[3]);
        u.w[2] = cvtpk(b[0], b[1]); u.w[3] = cvtpk(b[2], b[3]);
        *(bf16x8*)&out[idx] = u.v;
    } else {
        int idx = (bid - 6144) * 256 + tid;   // 65536
        int l = idx >> 5, d = idx & 31;
        float inv = expf(-(float)d / 32.f * logf(10000.f));
        float ang = (float)l * inv;
        tab[idx * 2 + 0] = cosf(ang);
        tab[idx * 2 + 1] = sinf(ang);
    }
}

// ---------------- GEMM: C[M,N] = A[M,K]*B[N,K]^T + bias, bf16 in ----------
// BM=BN=128, BK=32, 4 waves (2x2), per-wave 64x64 output, 256 threads.
// PAIR-INTERLEAVED LDS: row-pairs share one 128B line -> 8 slot-columns ->
// conflict-free b128 reads (BK=32's 64B rows alone give only 4 columns =
// the 2x serialization R12 measured). Line p holds rows {2p, 2p+1}; slot
// s stores (row parity = s0>>2, kgrp = s0&3) with s = s0 ^ (p&7).
// 2-slot ring = 32 KB total -> 5 blocks/CU (20 waves) = attn's occupancy
// regime. Window (x32): {barrier; STAGE 4 loads; vmcnt(4); barrier;
// 8 ds_read_b128 + 16 MFMA (setprio)} — exactly the attn window shape.
// XCD N-PARTITION: xcd = bid&7 owns a fixed n-chunk -> B L2-resident.
// MODE 0: fp32 out + bias. MODE 1: fused QKV epilogue (RoPE q/k, +QSCALE on
// q, bf16 qkv; v section written transposed to VT[bh][d][L]).
template<int MODE>
__global__ __launch_bounds__(256, 5)
void gemm_bt(const short* __restrict__ A,
             const short* __restrict__ B,
             const float* __restrict__ bias,
             void* __restrict__ Cout,
             short* __restrict__ VTout,
             const float* __restrict__ tab,
             int M, int N, int K) {
    __shared__ short lds[2 * 8192];   // slot = A[64 lines x 128B] + B same = 16 KB
    const int tid = threadIdx.x;
    const int lane = tid & 63, wave = tid >> 6;
    const int i15 = lane & 15, g = lane >> 4;
    const int wr = wave >> 1, wc = wave & 1;

    // XCD n-partition: xcd = bid&7 owns n-chunk of nbx/8 n-blocks.
    const int nbx = gridDim.x;
    int bid = blockIdx.y * nbx + blockIdx.x;
    const int xcd = bid & 7, idx = bid >> 3;
    const int nchunk = nbx >> 3;
    const int n0 = (xcd * nchunk + (idx % nchunk)) * 128;
    const int m0 = (idx / nchunk) * 128;

    // LDS read bases (pair-interleave): line p = wr*32 + m*8 + (i15>>1),
    // slot sr = ((i15&1)*4 + g) ^ (p&7); (m*8)&7==0 so sr is m-invariant.
    const int pb = i15 >> 1;
    const int sr = (((i15 & 1) << 2) | g) ^ pb;
    const int aoff = (wr * 32 + pb) * 64 + sr * 8;   // shorts; af[m] = +m*512
    const int boff = (wc * 32 + pb) * 64 + sr * 8;

    // staging sources (inverse pair-swizzle). Load i covers lines
    // p = i*32 + (t>>3); stored slot t&7 holds s0 = (t&7)^(p&7):
    // global row = 2p + (s0>>2), k-grp = s0&3.
    const int s0 = (tid & 7) ^ ((tid >> 3) & 7);
    const int row0 = 2 * (tid >> 3) + (s0 >> 2);   // i=0 lines 0..31
    const int kc = (s0 & 3) * 8;
    const short* pA0 = A + (size_t)(m0 + row0) * K + kc;
    const short* pA1 = A + (size_t)(m0 + row0 + 64) * K + kc;
    const short* pB0 = B + (size_t)(n0 + row0) * K + kc;
    const short* pB1 = B + (size_t)(n0 + row0 + 64) * K + kc;

    // dest (shorts): A chunk i at slot*8192 + i*2048 + t*8; B at +4096.
#define STAGE(slot)                                                   \
    do {                                                              \
        gld_lds16(pA0, lds + (slot) * 8192 + 0 * 2048 + tid * 8 - (lane * 8) + (lane * 8)); \
        gld_lds16(pA1, lds + (slot) * 8192 + 1 * 2048 + tid * 8 - (lane * 8) + (lane * 8)); \
        gld_lds16(pB0, lds + (slot) * 8192 + 4096 + 0 * 2048 + tid * 8 - (lane * 8) + (lane * 8)); \
        gld_lds16(pB1, lds + (slot) * 8192 + 4096 + 1 * 2048 + tid * 8 - (lane * 8) + (lane * 8)); \
        pA0 += 32; pA1 += 32; pB0 += 32; pB1 += 32;                   \
    } while (0)
    // note: dest = wave-uniform base + lane*16B; tid*8 shorts == wave*512 + lane*8,
    // expressed directly (the compiler folds the identical +/- lane terms).

    STAGE(0);

    f32x4 acc[4][4] = {};
    const int NT = K >> 5;   // 32 windows for K=1024

    for (int T = 0; T < NT; ++T) {
        const int cur = T & 1;
        if (T > 0) {
            __builtin_amdgcn_s_barrier();          // all waves done reading slot cur
            __builtin_amdgcn_sched_barrier(0);
        }
        if (T + 1 < NT) {
            STAGE(cur ^ 1);                        // 4 loads for tile T+1
            asm volatile("s_waitcnt vmcnt(4)" ::: "memory");  // tile T landed
        } else {
            asm volatile("s_waitcnt vmcnt(0)" ::: "memory");
        }
        __builtin_amdgcn_s_barrier();
        __builtin_amdgcn_sched_barrier(0);

        const short* As_ = lds + cur * 8192;
        const short* Bs_ = As_ + 4096;
        bf16x8 af[4], bfr[4];
#pragma unroll
        for (int m = 0; m < 4; ++m) af[m] = *(const bf16x8*)&As_[aoff + m * 512];
#pragma unroll
        for (int n = 0; n < 4; ++n) bfr[n] = *(const bf16x8*)&Bs_[boff + n * 512];
        __builtin_amdgcn_s_setprio(1);
#pragma unroll
        for (int m = 0; m < 4; ++m)
#pragma unroll
            for (int n = 0; n < 4; ++n)
                acc[m][n] = __builtin_amdgcn_mfma_f32_16x16x32_bf16(af[m], bfr[n], acc[m][n], 0, 0, 0);
        __builtin_amdgcn_s_setprio(0);
    }
#undef STAGE

    // epilogue: C row = m0+wr*64+m*16+g*4+j, col = n0+wc*64+n*16+i15
    if (MODE == 0) {
#pragma unroll
        for (int m = 0; m < 4; ++m)
#pragma unroll
            for (int n = 0; n < 4; ++n) {
                int col = n0 + wc * 64 + n * 16 + i15;
                float bcol = bias[col];
#pragma unroll
                for (int j = 0; j < 4; ++j) {
                    int row = m0 + wr * 64 + m * 16 + g * 4 + j;
                    ((float*)Cout)[(size_t)row * N + col] = acc[m][n][j] + bcol;
                }
            }
    } else {
        const int sec = n0 >> 10;        // 0=q, 1=k, 2=v (128-blocks never straddle)
        if (sec < 2) {
            const float qs = (sec == 0) ? QSCALE : 1.0f;
            short* out = (short*)Cout;
#pragma unroll
            for (int m = 0; m < 4; ++m) {
#pragma unroll
                for (int pp = 0; pp < 2; ++pp) {     // pairs (n=pp, n=pp+2): cols d, d+32
                    int d = pp * 16 + i15;
                    int collo = n0 + wc * 64 + pp * 16 + i15;
                    float blo = bias[collo], bhi = bias[collo + 32];
#pragma unroll
                    for (int j = 0; j < 4; ++j) {
                        int row = m0 + wr * 64 + m * 16 + g * 4 + j;
                        int l = row & 2047;
                        float2 cs = *(const float2*)&tab[(l * 32 + d) * 2];
                        float x1 = acc[m][pp][j] + blo;
                        float x2 = acc[m][pp + 2][j] + bhi;
                        out[(size_t)row * 3072 + collo]      = f2bf((x1 * cs.x - x2 * cs.y) * qs);
                        out[(size_t)row * 3072 + collo + 32] = f2bf((x2 * cs.x + x1 * cs.y) * qs);
                    }
                }
            }
        } else {
            // v section: write V^T directly. VT[(b*16+h)*64 + d][l], 4 l per lane.
#pragma unroll
            for (int m = 0; m < 4; ++m) {
                int rbase = m0 + wr * 64 + m * 16 + g * 4;
                int lbase = rbase & 2047, bidx = rbase >> 11;
#pragma unroll
                for (int n = 0; n < 4; ++n) {
                    int vcol = (n0 - 2048) + wc * 64 + n * 16 + i15;
                    int h = vcol >> 6, d = vcol & 63;
                    float bb = bias[n0 + wc * 64 + n * 16 + i15];
                    union { unsigned w[2]; s16x4 v; } u;
                    u.w[0] = cvtpk(acc[m][n][0] + bb, acc[m][n][1] + bb);
                    u.w[1] = cvtpk(acc[m][n][2] + bb, acc[m][n][3] + bb);
                    *(s16x4*)&VTout[((size_t)(bidx * 16 + h) * 64 + d) * 2048 + lbase] = u.v;
                }
            }
        }
    }
}

// ---------------- flash attention: 32 q-rows per wave (unchanged R10) ----
__global__ __launch_bounds__(256, 4) void attn_kernel(const short* __restrict__ qkv,
                                                      const short* __restrict__ VT,
                                                      short* __restrict__ O) {
    __shared__ short Ks[2][64 * 64];
    __shared__ short Vs[2][64 * 64];
    int orig = blockIdx.x;
    int xcd = orig & 7, idx = orig >> 3;        // idx in [0,128)
    int bh = xcd * 8 + (idx >> 4), qt = idx & 15;
    int b = bh >> 4, h = bh & 15;
    int tid = threadIdx.x, lane = tid & 63, wave = tid >> 6;
    int i15 = lane & 15, g = lane >> 4;
    int q0 = qt * 128;

    size_t qbase = (size_t)(b * 2048 + q0 + wave * 32);
    bf16x8 qf[2][2];
#pragma unroll
    for (int qg = 0; qg < 2; ++qg) {
        qf[qg][0] = *(const bf16x8*)&qkv[(qbase + qg * 16 + i15) * 3072 + h * 64 + 0  + g * 8];
        qf[qg][1] = *(const bf16x8*)&qkv[(qbase + qg * 16 + i15) * 3072 + h * 64 + 32 + g * 8];
    }

    bf16x8 onesf;
#pragma unroll
    for (int e = 0; e < 8; ++e) onesf[e] = (short)0x3F80;   // bf16 1.0

    const int srow = tid >> 3;
    const int ss8 = (tid & 7) ^ (srow & 7);
    const int pr0 = (srow & 0x23) | ((srow & 0x10) >> 2) | ((srow & 0x0C) << 1);
    const int sr1 = srow + 32;
    const int pr1 = (sr1 & 0x23) | ((sr1 & 0x10) >> 2) | ((sr1 & 0x0C) << 1);
    const short* kb_ = qkv + (size_t)(b * 2048) * 3072 + 1024 + h * 64 + ss8 * 8;
    const short* kp0 = kb_ + (size_t)pr0 * 3072;
    const short* kp1 = kb_ + (size_t)pr1 * 3072;
    const short* vb_ = VT + (size_t)bh * 64 * 2048 + ss8 * 8;
    const short* vp0 = vb_ + (size_t)srow * 2048;
    const short* vp1 = vb_ + (size_t)sr1 * 2048;

    const int xr3 = i15 & 3, xb2 = (i15 >> 2) & 1;
    const int cLo = g ^ xr3;
    const int o0 = i15 * 64 + (xb2 * 4 + cLo) * 8;
    const int o1 = i15 * 64 + ((1 ^ xb2) * 4 + cLo) * 8;

    f32x4 acc_o[2][4] = {};
    f32x4 acc_l[2] = {};

#define STAGE(bk, bv)                                        \
    do {                                                     \
        gld_lds16(kp0, (bk) + wave * 512);                   \
        gld_lds16(kp1, (bk) + 2048 + wave * 512);            \
        gld_lds16(vp0, (bv) + wave * 512);                   \
        gld_lds16(vp1, (bv) + 2048 + wave * 512);            \
        kp0 += (size_t)64 * 3072; kp1 += (size_t)64 * 3072;  \
        vp0 += 64; vp1 += 64;                                \
    } while (0)

    STAGE(Ks[0], Vs[0]);

    for (int t = 0; t < 32; ++t) {
        const int cur = t & 1;
        if (t > 0) {
            __builtin_amdgcn_s_barrier();
            __builtin_amdgcn_sched_barrier(0);
        }
        if (t + 1 < 32) {
            STAGE(Ks[cur ^ 1], Vs[cur ^ 1]);
            asm volatile("s_waitcnt vmcnt(4)" ::: "memory");
        } else {
            asm volatile("s_waitcnt vmcnt(0)" ::: "memory");
        }
        __builtin_amdgcn_s_barrier();
        __builtin_amdgcn_sched_barrier(0);

        const short* ks = Ks[cur];
        const short* vs = Vs[cur];

        f32x4 sa[2][4] = {};
        __builtin_amdgcn_s_setprio(1);
#pragma unroll
        for (int kb = 0; kb < 2; ++kb) {
            const int ko = kb ? o1 : o0;
            bf16x8 kf[4];
#pragma unroll
            for (int jb = 0; jb < 4; ++jb) kf[jb] = *(const bf16x8*)&ks[ko + jb * 1024];
#pragma unroll
            for (int qg = 0; qg < 2; ++qg)
#pragma unroll
                for (int jb = 0; jb < 4; ++jb)
                    sa[qg][jb] = __builtin_amdgcn_mfma_f32_16x16x32_bf16(kf[jb], qf[qg][kb], sa[qg][jb], 0, 0, 0);
        }
        __builtin_amdgcn_s_setprio(0);

        bf16x8 pf[2][2];
#pragma unroll
        for (int qg = 0; qg < 2; ++qg) {
            float p[4][4];
#pragma unroll
            for (int jb = 0; jb < 4; ++jb)
#pragma unroll
                for (int r = 0; r < 4; ++r)
                    p[jb][r] = __builtin_amdgcn_exp2f(sa[qg][jb][r]);
#pragma unroll
            for (int kb = 0; kb < 2; ++kb) {
                union { unsigned w[4]; bf16x8 v; } u;
                u.w[0] = cvtpk(p[2 * kb][0],     p[2 * kb][1]);
                u.w[1] = cvtpk(p[2 * kb][2],     p[2 * kb][3]);
                u.w[2] = cvtpk(p[2 * kb + 1][0], p[2 * kb + 1][1]);
                u.w[3] = cvtpk(p[2 * kb + 1][2], p[2 * kb + 1][3]);
                pf[qg][kb] = u.v;
            }
        }

        __builtin_amdgcn_s_setprio(1);
#pragma unroll
        for (int db = 0; db < 4; ++db) {
#pragma unroll
            for (int kb = 0; kb < 2; ++kb) {
                bf16x8 vf = *(const bf16x8*)&vs[(kb ? o1 : o0) + db * 1024];
#pragma unroll
                for (int qg = 0; qg < 2; ++qg)
                    acc_o[qg][db] = __builtin_amdgcn_mfma_f32_16x16x32_bf16(pf[qg][kb], vf, acc_o[qg][db], 0, 0, 0);
            }
        }
#pragma unroll
        for (int qg = 0; qg < 2; ++qg) {
            acc_l[qg] = __builtin_amdgcn_mfma_f32_16x16x32_bf16(pf[qg][0], onesf, acc_l[qg], 0, 0, 0);
            acc_l[qg] = __builtin_amdgcn_mfma_f32_16x16x32_bf16(pf[qg][1], onesf, acc_l[qg], 0, 0, 0);
        }
        __builtin_amdgcn_s_setprio(0);
    }
#undef STAGE

#pragma unroll
    for (int qg = 0; qg < 2; ++qg) {
        float linv4[4];
#pragma unroll
        for (int r = 0; r < 4; ++r) linv4[r] = 1.f / acc_l[qg][r];
#pragma unroll
        for (int db = 0; db < 4; ++db) {
            int ocol = h * 64 + db * 16 + i15;
#pragma unroll
            for (int r = 0; r < 4; ++r) {
                size_t orow = qbase + qg * 16 + g * 4 + r;
                O[orow * 1024 + ocol] = f2bf(acc_o[qg][db][r] * linv4[r]);
            }
        }
    }
}

extern "C" void kernel_launch(void* const* d_in, const int* in_sizes, int n_in,
                              void* d_out, int out_size, void* d_ws, size_t ws_size,
                              hipStream_t stream) {
    const float* x     = (const float*)d_in[0];
    const float* w_qkv = (const float*)d_in[1];
    const float* b_qkv = (const float*)d_in[2];
    const float* w_out = (const float*)d_in[3];
    const float* b_out = (const float*)d_in[4];

    char* ws = (char*)d_ws;
    short* qkvb = (short*)(ws);                 // 8192*3072*2  = 50331648 (v sec unused)
    short* xb   = (short*)(ws + 50331648);      // 8192*1024*2  = 16777216 (reused as O)
    short* wqb  = (short*)(ws + 67108864);      // 3072*1024*2  =  6291456
    short* wob  = (short*)(ws + 73400320);      // 1024*1024*2  =  2097152
    short* VT   = (short*)(ws + 75497472);      // 64*64*2048*2 = 16777216
    float* rt   = (float*)(ws + 92274688);      // 2048*32*2*4  =   524288
    short* Ob   = xb;                           // reuse x_bf16 region for attn output

    prep_kernel<<<6400, 256, 0, stream>>>(x, w_qkv, w_out, xb, wqb, wob, rt);

    gemm_bt<1><<<dim3(24, 64), 256, 0, stream>>>(xb, wqb, b_qkv, qkvb, VT, rt, 8192, 3072, 1024);
    attn_kernel<<<1024, 256, 0, stream>>>(qkvb, VT, Ob);
    gemm_bt<0><<<dim3(8, 64), 256, 0, stream>>>(Ob, wob, b_out, d_out, nullptr, nullptr, 8192, 1024, 1024);
}

// Round 14
// 234.404 us; speedup vs baseline: 1.7064x; 1.7064x over previous
//
#include <hip/hip_runtime.h>
#include <stdint.h>

typedef __attribute__((ext_vector_type(4))) float f32x4;
typedef __attribute__((ext_vector_type(8))) short bf16x8;
typedef __attribute__((ext_vector_type(4))) short s16x4;
typedef __attribute__((ext_vector_type(4))) float fp32x4;

#define QSCALE 0.18033688f   // 0.125 * log2(e): scores exit QK^T in log2 domain

__device__ __forceinline__ short f2bf(float f) {
    union { float f; unsigned u; } v; v.f = f;
    unsigned u = v.u;
    unsigned r = u + 0x7fffu + ((u >> 16) & 1u);
    return (short)(r >> 16);
}
// packed bf16 convert (RNE), lo = a, hi = b
__device__ __forceinline__ unsigned cvtpk(float a, float b) {
    unsigned r;
    asm("v_cvt_pk_bf16_f32 %0, %1, %2" : "=v"(r) : "v"(a), "v"(b));
    return r;
}

// async global->LDS, 16B per lane. dest = wave-uniform base + lane*16.
__device__ __forceinline__ void gld_lds16(const void* g, void* l) {
    __builtin_amdgcn_global_load_lds(
        (const __attribute__((address_space(1))) unsigned int*)(uintptr_t)g,
        (__attribute__((address_space(3))) unsigned int*)(uintptr_t)l,
        16, 0, 0);
}

// ---------------- fused prep: all casts + RoPE table in ONE launch --------
__global__ __launch_bounds__(256) void prep_kernel(const float* __restrict__ x,
                                                   const float* __restrict__ wq,
                                                   const float* __restrict__ wo,
                                                   short* __restrict__ xb,
                                                   short* __restrict__ wqb,
                                                   short* __restrict__ wob,
                                                   float* __restrict__ tab) {
    int bid = blockIdx.x, tid = threadIdx.x;
    if (bid < 6144) {
        const float* in; short* out; int base;
        if (bid < 4096)      { in = x;  out = xb;  base = bid; }
        else if (bid < 5632) { in = wq; out = wqb; base = bid - 4096; }
        else                 { in = wo; out = wob; base = bid - 5632; }
        int idx = (base * 256 + tid) * 8;
        fp32x4 a = *(const fp32x4*)&in[idx];
        fp32x4 b = *(const fp32x4*)&in[idx + 4];
        union { unsigned w[4]; bf16x8 v; } u;
        u.w[0] = cvtpk(a[0], a[1]); u.w[1] = cvtpk(a[2], a[3]);
        u.w[2] = cvtpk(b[0], b[1]); u.w[3] = cvtpk(b[2], b[3]);
        *(bf16x8*)&out[idx] = u.v;
    } else {
        int idx = (bid - 6144) * 256 + tid;   // 65536
        int l = idx >> 5, d = idx & 31;
        float inv = expf(-(float)d / 32.f * logf(10000.f));
        float ang = (float)l * inv;
        tab[idx * 2 + 0] = cosf(ang);
        tab[idx * 2 + 1] = sinf(ang);
    }
}

// ---------------- GEMM: C[M,N] = A[M,K]*B[N,K]^T + bias, bf16 in ----------
// BM=BN=128, BK=64, 4 waves (2x2), per-wave 64x64 output, 256 threads.
// A-DIRECT: A fragments are K-contiguous 16B per lane -> loaded straight
// from global to registers (L2-served; same-XCD neighbor blocks share the
// A panel). Only B is staged through LDS (R10's proven swizzle). This cuts
// LDS traffic ~2x (the measured binding pipe: 2.4 GB -> 1.2 GB).
// 2-slot B ring = 32 KB -> ~3 blocks/CU. Window: {barrier; af 8 reg-loads;
// stage B(T+1) 4; vmcnt(4) [af(T)+B(T) retired, B(T+1) in flight];
// barrier; 8 ds_read + 32 MFMA (setprio)}. In-order vmcnt: af issued FIRST.
// XCD N-PARTITION: xcd = bid&7 owns a fixed n-chunk -> B L2-resident.
// MODE 0: fp32 out + bias. MODE 1: fused QKV epilogue (RoPE q/k, +QSCALE on
// q, bf16 qkv; v section written transposed to VT[bh][d][L]).
template<int MODE>
__global__ __launch_bounds__(256)
void gemm_bt(const short* __restrict__ A,
             const short* __restrict__ B,
             const float* __restrict__ bias,
             void* __restrict__ Cout,
             short* __restrict__ VTout,
             const float* __restrict__ tab,
             int M, int N, int K) {
    __shared__ short lds[2 * 8192];   // 2 slots x B[128x64] = 32 KB
    const int tid = threadIdx.x;
    const int lane = tid & 63, wave = tid >> 6;
    const int i15 = lane & 15, g = lane >> 4;
    const int wr = wave >> 1, wc = wave & 1;

    // XCD n-partition: xcd = bid&7 owns n-chunk of nbx/8 n-blocks.
    const int nbx = gridDim.x;
    int bid = blockIdx.y * nbx + blockIdx.x;
    const int xcd = bid & 7, idx = bid >> 3;
    const int nchunk = nbx >> 3;
    const int n0 = (xcd * nchunk + (idx % nchunk)) * 128;
    const int m0 = (idx / nchunk) * 128;

    // B LDS read bases (proven split-XOR): swizzled col = (ks*4+g)^(i15&7)
    const int xr3 = i15 & 3, xb2 = (i15 >> 2) & 1;
    const int cLo = g ^ xr3;
    const int boff0 = (wc * 64 + i15) * 64 + (xb2 * 4 + cLo) * 8;
    const int boff1 = (wc * 64 + i15) * 64 + ((1 ^ xb2) * 4 + cLo) * 8;

    // B staging (proven): thread covers rows r*32 + (tid>>3), col-grp tid&7
    const int srow = tid >> 3;
    const int ss = (tid & 7) ^ (srow & 7);
    const short* b0 = B + (size_t)(n0 + srow) * K + ss * 8;
    const short* b1 = b0 + (size_t)32 * K;
    const short* b2 = b0 + (size_t)64 * K;
    const short* b3 = b0 + (size_t)96 * K;

    // A direct-to-register pointers: row = m0 + wr*64 + m*16 + i15, k-base g*8
    const short* aP0 = A + (size_t)(m0 + wr * 64 + 0 * 16 + i15) * K + g * 8;
    const short* aP1 = A + (size_t)(m0 + wr * 64 + 1 * 16 + i15) * K + g * 8;
    const short* aP2 = A + (size_t)(m0 + wr * 64 + 2 * 16 + i15) * K + g * 8;
    const short* aP3 = A + (size_t)(m0 + wr * 64 + 3 * 16 + i15) * K + g * 8;

#define STAGE_B(slot)                                                 \
    do {                                                              \
        gld_lds16(b0, lds + (slot) * 8192 + 0 * 2048 + wave * 512);   \
        gld_lds16(b1, lds + (slot) * 8192 + 1 * 2048 + wave * 512);   \
        gld_lds16(b2, lds + (slot) * 8192 + 2 * 2048 + wave * 512);   \
        gld_lds16(b3, lds + (slot) * 8192 + 3 * 2048 + wave * 512);   \
        b0 += 64; b1 += 64; b2 += 64; b3 += 64;                       \
    } while (0)

    STAGE_B(0);   // B(0), oldest in queue

    f32x4 acc[4][4] = {};
    const int NT = K >> 6;

    for (int T = 0; T < NT; ++T) {
        const int cur = T & 1;
        if (T > 0) {
            __builtin_amdgcn_s_barrier();          // all waves done reading slot cur
            __builtin_amdgcn_sched_barrier(0);
        }
        // af(T): 8 global->reg loads, issued FIRST (in-order vmcnt queue)
        bf16x8 af[4][2];
        af[0][0] = *(const bf16x8*)aP0; af[0][1] = *(const bf16x8*)(aP0 + 32);
        af[1][0] = *(const bf16x8*)aP1; af[1][1] = *(const bf16x8*)(aP1 + 32);
        af[2][0] = *(const bf16x8*)aP2; af[2][1] = *(const bf16x8*)(aP2 + 32);
        af[3][0] = *(const bf16x8*)aP3; af[3][1] = *(const bf16x8*)(aP3 + 32);
        aP0 += 64; aP1 += 64; aP2 += 64; aP3 += 64;
        __builtin_amdgcn_sched_barrier(0);
        if (T + 1 < NT) {
            STAGE_B(cur ^ 1);                      // B(T+1): 4 newest
            __builtin_amdgcn_sched_barrier(0);
            asm volatile("s_waitcnt vmcnt(4)" ::: "memory");  // af(T)+B(T) retired
        } else {
            asm volatile("s_waitcnt vmcnt(0)" ::: "memory");
        }
        __builtin_amdgcn_s_barrier();              // all waves' B(T) writes visible
        __builtin_amdgcn_sched_barrier(0);

        const short* Bs_ = lds + cur * 8192;
        bf16x8 bfr[4][2];
#pragma unroll
        for (int n = 0; n < 4; ++n) {
            bfr[n][0] = *(const bf16x8*)&Bs_[boff0 + n * 1024];
            bfr[n][1] = *(const bf16x8*)&Bs_[boff1 + n * 1024];
        }
        __builtin_amdgcn_s_setprio(1);
#pragma unroll
        for (int m = 0; m < 4; ++m)
#pragma unroll
            for (int n = 0; n < 4; ++n)
#pragma unroll
                for (int ks = 0; ks < 2; ++ks)
                    acc[m][n] = __builtin_amdgcn_mfma_f32_16x16x32_bf16(af[m][ks], bfr[n][ks], acc[m][n], 0, 0, 0);
        __builtin_amdgcn_s_setprio(0);
    }
#undef STAGE_B

    // epilogue: C row = m0+wr*64+m*16+g*4+j, col = n0+wc*64+n*16+i15
    if (MODE == 0) {
#pragma unroll
        for (int m = 0; m < 4; ++m)
#pragma unroll
            for (int n = 0; n < 4; ++n) {
                int col = n0 + wc * 64 + n * 16 + i15;
                float bcol = bias[col];
#pragma unroll
                for (int j = 0; j < 4; ++j) {
                    int row = m0 + wr * 64 + m * 16 + g * 4 + j;
                    ((float*)Cout)[(size_t)row * N + col] = acc[m][n][j] + bcol;
                }
            }
    } else {
        const int sec = n0 >> 10;        // 0=q, 1=k, 2=v (128-blocks never straddle)
        if (sec < 2) {
            const float qs = (sec == 0) ? QSCALE : 1.0f;
            short* out = (short*)Cout;
#pragma unroll
            for (int m = 0; m < 4; ++m) {
#pragma unroll
                for (int pp = 0; pp < 2; ++pp) {     // pairs (n=pp, n=pp+2): cols d, d+32
                    int d = pp * 16 + i15;
                    int collo = n0 + wc * 64 + pp * 16 + i15;
                    float blo = bias[collo], bhi = bias[collo + 32];
#pragma unroll
                    for (int j = 0; j < 4; ++j) {
                        int row = m0 + wr * 64 + m * 16 + g * 4 + j;
                        int l = row & 2047;
                        float2 cs = *(const float2*)&tab[(l * 32 + d) * 2];
                        float x1 = acc[m][pp][j] + blo;
                        float x2 = acc[m][pp + 2][j] + bhi;
                        out[(size_t)row * 3072 + collo]      = f2bf((x1 * cs.x - x2 * cs.y) * qs);
                        out[(size_t)row * 3072 + collo + 32] = f2bf((x2 * cs.x + x1 * cs.y) * qs);
                    }
                }
            }
        } else {
            // v section: write V^T directly. VT[(b*16+h)*64 + d][l], 4 l per lane.
#pragma unroll
            for (int m = 0; m < 4; ++m) {
                int rbase = m0 + wr * 64 + m * 16 + g * 4;
                int lbase = rbase & 2047, bidx = rbase >> 11;
#pragma unroll
                for (int n = 0; n < 4; ++n) {
                    int vcol = (n0 - 2048) + wc * 64 + n * 16 + i15;
                    int h = vcol >> 6, d = vcol & 63;
                    float bb = bias[n0 + wc * 64 + n * 16 + i15];
                    union { unsigned w[2]; s16x4 v; } u;
                    u.w[0] = cvtpk(acc[m][n][0] + bb, acc[m][n][1] + bb);
                    u.w[1] = cvtpk(acc[m][n][2] + bb, acc[m][n][3] + bb);
                    *(s16x4*)&VTout[((size_t)(bidx * 16 + h) * 64 + d) * 2048 + lbase] = u.v;
                }
            }
        }
    }
}

// ---------------- flash attention: 32 q-rows per wave (unchanged R10) ----
__global__ __launch_bounds__(256, 4) void attn_kernel(const short* __restrict__ qkv,
                                                      const short* __restrict__ VT,
                                                      short* __restrict__ O) {
    __shared__ short Ks[2][64 * 64];
    __shared__ short Vs[2][64 * 64];
    int orig = blockIdx.x;
    int xcd = orig & 7, idx = orig >> 3;        // idx in [0,128)
    int bh = xcd * 8 + (idx >> 4), qt = idx & 15;
    int b = bh >> 4, h = bh & 15;
    int tid = threadIdx.x, lane = tid & 63, wave = tid >> 6;
    int i15 = lane & 15, g = lane >> 4;
    int q0 = qt * 128;

    size_t qbase = (size_t)(b * 2048 + q0 + wave * 32);
    bf16x8 qf[2][2];
#pragma unroll
    for (int qg = 0; qg < 2; ++qg) {
        qf[qg][0] = *(const bf16x8*)&qkv[(qbase + qg * 16 + i15) * 3072 + h * 64 + 0  + g * 8];
        qf[qg][1] = *(const bf16x8*)&qkv[(qbase + qg * 16 + i15) * 3072 + h * 64 + 32 + g * 8];
    }

    bf16x8 onesf;
#pragma unroll
    for (int e = 0; e < 8; ++e) onesf[e] = (short)0x3F80;   // bf16 1.0

    const int srow = tid >> 3;
    const int ss8 = (tid & 7) ^ (srow & 7);
    const int pr0 = (srow & 0x23) | ((srow & 0x10) >> 2) | ((srow & 0x0C) << 1);
    const int sr1 = srow + 32;
    const int pr1 = (sr1 & 0x23) | ((sr1 & 0x10) >> 2) | ((sr1 & 0x0C) << 1);
    const short* kb_ = qkv + (size_t)(b * 2048) * 3072 + 1024 + h * 64 + ss8 * 8;
    const short* kp0 = kb_ + (size_t)pr0 * 3072;
    const short* kp1 = kb_ + (size_t)pr1 * 3072;
    const short* vb_ = VT + (size_t)bh * 64 * 2048 + ss8 * 8;
    const short* vp0 = vb_ + (size_t)srow * 2048;
    const short* vp1 = vb_ + (size_t)sr1 * 2048;

    const int xr3 = i15 & 3, xb2 = (i15 >> 2) & 1;
    const int cLo = g ^ xr3;
    const int o0 = i15 * 64 + (xb2 * 4 + cLo) * 8;
    const int o1 = i15 * 64 + ((1 ^ xb2) * 4 + cLo) * 8;

    f32x4 acc_o[2][4] = {};
    f32x4 acc_l[2] = {};

#define STAGE(bk, bv)                                        \
    do {                                                     \
        gld_lds16(kp0, (bk) + wave * 512);                   \
        gld_lds16(kp1, (bk) + 2048 + wave * 512);            \
        gld_lds16(vp0, (bv) + wave * 512);                   \
        gld_lds16(vp1, (bv) + 2048 + wave * 512);            \
        kp0 += (size_t)64 * 3072; kp1 += (size_t)64 * 3072;  \
        vp0 += 64; vp1 += 64;                                \
    } while (0)

    STAGE(Ks[0], Vs[0]);

    for (int t = 0; t < 32; ++t) {
        const int cur = t & 1;
        if (t > 0) {
            __builtin_amdgcn_s_barrier();
            __builtin_amdgcn_sched_barrier(0);
        }
        if (t + 1 < 32) {
            STAGE(Ks[cur ^ 1], Vs[cur ^ 1]);
            asm volatile("s_waitcnt vmcnt(4)" ::: "memory");
        } else {
            asm volatile("s_waitcnt vmcnt(0)" ::: "memory");
        }
        __builtin_amdgcn_s_barrier();
        __builtin_amdgcn_sched_barrier(0);

        const short* ks = Ks[cur];
        const short* vs = Vs[cur];

        f32x4 sa[2][4] = {};
        __builtin_amdgcn_s_setprio(1);
#pragma unroll
        for (int kb = 0; kb < 2; ++kb) {
            const int ko = kb ? o1 : o0;
            bf16x8 kf[4];
#pragma unroll
            for (int jb = 0; jb < 4; ++jb) kf[jb] = *(const bf16x8*)&ks[ko + jb * 1024];
#pragma unroll
            for (int qg = 0; qg < 2; ++qg)
#pragma unroll
                for (int jb = 0; jb < 4; ++jb)
                    sa[qg][jb] = __builtin_amdgcn_mfma_f32_16x16x32_bf16(kf[jb], qf[qg][kb], sa[qg][jb], 0, 0, 0);
        }
        __builtin_amdgcn_s_setprio(0);

        bf16x8 pf[2][2];
#pragma unroll
        for (int qg = 0; qg < 2; ++qg) {
            float p[4][4];
#pragma unroll
            for (int jb = 0; jb < 4; ++jb)
#pragma unroll
                for (int r = 0; r < 4; ++r)
                    p[jb][r] = __builtin_amdgcn_exp2f(sa[qg][jb][r]);
#pragma unroll
            for (int kb = 0; kb < 2; ++kb) {
                union { unsigned w[4]; bf16x8 v; } u;
                u.w[0] = cvtpk(p[2 * kb][0],     p[2 * kb][1]);
                u.w[1] = cvtpk(p[2 * kb][2],     p[2 * kb][3]);
                u.w[2] = cvtpk(p[2 * kb + 1][0], p[2 * kb + 1][1]);
                u.w[3] = cvtpk(p[2 * kb + 1][2], p[2 * kb + 1][3]);
                pf[qg][kb] = u.v;
            }
        }

        __builtin_amdgcn_s_setprio(1);
#pragma unroll
        for (int db = 0; db < 4; ++db) {
#pragma unroll
            for (int kb = 0; kb < 2; ++kb) {
                bf16x8 vf = *(const bf16x8*)&vs[(kb ? o1 : o0) + db * 1024];
#pragma unroll
                for (int qg = 0; qg < 2; ++qg)
                    acc_o[qg][db] = __builtin_amdgcn_mfma_f32_16x16x32_bf16(pf[qg][kb], vf, acc_o[qg][db], 0, 0, 0);
            }
        }
#pragma unroll
        for (int qg = 0; qg < 2; ++qg) {
            acc_l[qg] = __builtin_amdgcn_mfma_f32_16x16x32_bf16(pf[qg][0], onesf, acc_l[qg], 0, 0, 0);
            acc_l[qg] = __builtin_amdgcn_mfma_f32_16x16x32_bf16(pf[qg][1], onesf, acc_l[qg], 0, 0, 0);
        }
        __builtin_amdgcn_s_setprio(0);
    }
#undef STAGE

#pragma unroll
    for (int qg = 0; qg < 2; ++qg) {
        float linv4[4];
#pragma unroll
        for (int r = 0; r < 4; ++r) linv4[r] = 1.f / acc_l[qg][r];
#pragma unroll
        for (int db = 0; db < 4; ++db) {
            int ocol = h * 64 + db * 16 + i15;
#pragma unroll
            for (int r = 0; r < 4; ++r) {
                size_t orow = qbase + qg * 16 + g * 4 + r;
                O[orow * 1024 + ocol] = f2bf(acc_o[qg][db][r] * linv4[r]);
            }
        }
    }
}

extern "C" void kernel_launch(void* const* d_in, const int* in_sizes, int n_in,
                              void* d_out, int out_size, void* d_ws, size_t ws_size,
                              hipStream_t stream) {
    const float* x     = (const float*)d_in[0];
    const float* w_qkv = (const float*)d_in[1];
    const float* b_qkv = (const float*)d_in[2];
    const float* w_out = (const float*)d_in[3];
    const float* b_out = (const float*)d_in[4];

    char* ws = (char*)d_ws;
    short* qkvb = (short*)(ws);                 // 8192*3072*2  = 50331648 (v sec unused)
    short* xb   = (short*)(ws + 50331648);      // 8192*1024*2  = 16777216 (reused as O)
    short* wqb  = (short*)(ws + 67108864);      // 3072*1024*2  =  6291456
    short* wob  = (short*)(ws + 73400320);      // 1024*1024*2  =  2097152
    short* VT   = (short*)(ws + 75497472);      // 64*64*2048*2 = 16777216
    float* rt   = (float*)(ws + 92274688);      // 2048*32*2*4  =   524288
    short* Ob   = xb;                           // reuse x_bf16 region for attn output

    prep_kernel<<<6400, 256, 0, stream>>>(x, w_qkv, w_out, xb, wqb, wob, rt);

    gemm_bt<1><<<dim3(24, 64), 256, 0, stream>>>(xb, wqb, b_qkv, qkvb, VT, rt, 8192, 3072, 1024);
    attn_kernel<<<1024, 256, 0, stream>>>(qkvb, VT, Ob);
    gemm_bt<0><<<dim3(8, 64), 256, 0, stream>>>(Ob, wob, b_out, d_out, nullptr, nullptr, 8192, 1024, 1024);
}

// Round 15
// 233.514 us; speedup vs baseline: 1.7129x; 1.0038x over previous
//
#include <hip/hip_runtime.h>
#include <stdint.h>

typedef __attribute__((ext_vector_type(4))) float f32x4;
typedef __attribute__((ext_vector_type(8))) short bf16x8;
typedef __attribute__((ext_vector_type(4))) short s16x4;
typedef __attribute__((ext_vector_type(4))) float fp32x4;

#define QSCALE 0.18033688f   // 0.125 * log2(e): scores exit QK^T in log2 domain

__device__ __forceinline__ short f2bf(float f) {
    union { float f; unsigned u; } v; v.f = f;
    unsigned u = v.u;
    unsigned r = u + 0x7fffu + ((u >> 16) & 1u);
    return (short)(r >> 16);
}
// packed bf16 convert (RNE), lo = a, hi = b
__device__ __forceinline__ unsigned cvtpk(float a, float b) {
    unsigned r;
    asm("v_cvt_pk_bf16_f32 %0, %1, %2" : "=v"(r) : "v"(a), "v"(b));
    return r;
}

// async global->LDS, 16B per lane. dest = wave-uniform base + lane*16.
__device__ __forceinline__ void gld_lds16(const void* g, void* l) {
    __builtin_amdgcn_global_load_lds(
        (const __attribute__((address_space(1))) unsigned int*)(uintptr_t)g,
        (__attribute__((address_space(3))) unsigned int*)(uintptr_t)l,
        16, 0, 0);
}

// ---------------- fused prep: all casts + RoPE table in ONE launch --------
__global__ __launch_bounds__(256) void prep_kernel(const float* __restrict__ x,
                                                   const float* __restrict__ wq,
                                                   const float* __restrict__ wo,
                                                   short* __restrict__ xb,
                                                   short* __restrict__ wqb,
                                                   short* __restrict__ wob,
                                                   float* __restrict__ tab) {
    int bid = blockIdx.x, tid = threadIdx.x;
    if (bid < 6144) {
        const float* in; short* out; int base;
        if (bid < 4096)      { in = x;  out = xb;  base = bid; }
        else if (bid < 5632) { in = wq; out = wqb; base = bid - 4096; }
        else                 { in = wo; out = wob; base = bid - 5632; }
        int idx = (base * 256 + tid) * 8;
        fp32x4 a = *(const fp32x4*)&in[idx];
        fp32x4 b = *(const fp32x4*)&in[idx + 4];
        union { unsigned w[4]; bf16x8 v; } u;
        u.w[0] = cvtpk(a[0], a[1]); u.w[1] = cvtpk(a[2], a[3]);
        u.w[2] = cvtpk(b[0], b[1]); u.w[3] = cvtpk(b[2], b[3]);
        *(bf16x8*)&out[idx] = u.v;
    } else {
        int idx = (bid - 6144) * 256 + tid;   // 65536
        int l = idx >> 5, d = idx & 31;
        float inv = expf(-(float)d / 32.f * logf(10000.f));
        float ang = (float)l * inv;
        tab[idx * 2 + 0] = cosf(ang);
        tab[idx * 2 + 1] = sinf(ang);
    }
}

// ---------------- GEMM: C[M,N] = A[M,K]*B[N,K]^T + bias, bf16 in ----------
// BM=BN=128, BK=64, 4 waves (2x2), per-wave 64x64 output, 256 threads.
// A-DIRECT: A fragments are K-contiguous 16B per lane -> loaded straight
// from global to registers (L2-served; same-XCD neighbor blocks share the
// A panel). Only B is staged through LDS (R10's proven swizzle). This cuts
// LDS traffic ~2x (the measured binding pipe: 2.4 GB -> 1.2 GB).
// 2-slot B ring = 32 KB -> ~3 blocks/CU. Window: {barrier; af 8 reg-loads;
// stage B(T+1) 4; vmcnt(4) [af(T)+B(T) retired, B(T+1) in flight];
// barrier; 8 ds_read + 32 MFMA (setprio)}. In-order vmcnt: af issued FIRST.
// XCD N-PARTITION: xcd = bid&7 owns a fixed n-chunk -> B L2-resident.
// MODE 0: fp32 out + bias. MODE 1: fused QKV epilogue (RoPE q/k, +QSCALE on
// q, bf16 qkv; v section written transposed to VT[bh][d][L]).
template<int MODE>
__global__ __launch_bounds__(256)
void gemm_bt(const short* __restrict__ A,
             const short* __restrict__ B,
             const float* __restrict__ bias,
             void* __restrict__ Cout,
             short* __restrict__ VTout,
             const float* __restrict__ tab,
             int M, int N, int K) {
    __shared__ short lds[2 * 8192];   // 2 slots x B[128x64] = 32 KB
    const int tid = threadIdx.x;
    const int lane = tid & 63, wave = tid >> 6;
    const int i15 = lane & 15, g = lane >> 4;
    const int wr = wave >> 1, wc = wave & 1;

    // XCD n-partition: xcd = bid&7 owns n-chunk of nbx/8 n-blocks.
    const int nbx = gridDim.x;
    int bid = blockIdx.y * nbx + blockIdx.x;
    const int xcd = bid & 7, idx = bid >> 3;
    const int nchunk = nbx >> 3;
    const int n0 = (xcd * nchunk + (idx % nchunk)) * 128;
    const int m0 = (idx / nchunk) * 128;

    // B LDS read bases (proven split-XOR): swizzled col = (ks*4+g)^(i15&7)
    const int xr3 = i15 & 3, xb2 = (i15 >> 2) & 1;
    const int cLo = g ^ xr3;
    const int boff0 = (wc * 64 + i15) * 64 + (xb2 * 4 + cLo) * 8;
    const int boff1 = (wc * 64 + i15) * 64 + ((1 ^ xb2) * 4 + cLo) * 8;

    // B staging (proven): thread covers rows r*32 + (tid>>3), col-grp tid&7
    const int srow = tid >> 3;
    const int ss = (tid & 7) ^ (srow & 7);
    const short* b0 = B + (size_t)(n0 + srow) * K + ss * 8;
    const short* b1 = b0 + (size_t)32 * K;
    const short* b2 = b0 + (size_t)64 * K;
    const short* b3 = b0 + (size_t)96 * K;

    // A direct-to-register pointers: row = m0 + wr*64 + m*16 + i15, k-base g*8
    const short* aP0 = A + (size_t)(m0 + wr * 64 + 0 * 16 + i15) * K + g * 8;
    const short* aP1 = A + (size_t)(m0 + wr * 64 + 1 * 16 + i15) * K + g * 8;
    const short* aP2 = A + (size_t)(m0 + wr * 64 + 2 * 16 + i15) * K + g * 8;
    const short* aP3 = A + (size_t)(m0 + wr * 64 + 3 * 16 + i15) * K + g * 8;

#define STAGE_B(slot)                                                 \
    do {                                                              \
        gld_lds16(b0, lds + (slot) * 8192 + 0 * 2048 + wave * 512);   \
        gld_lds16(b1, lds + (slot) * 8192 + 1 * 2048 + wave * 512);   \
        gld_lds16(b2, lds + (slot) * 8192 + 2 * 2048 + wave * 512);   \
        gld_lds16(b3, lds + (slot) * 8192 + 3 * 2048 + wave * 512);   \
        b0 += 64; b1 += 64; b2 += 64; b3 += 64;                       \
    } while (0)

    STAGE_B(0);   // B(0), oldest in queue

    f32x4 acc[4][4] = {};
    const int NT = K >> 6;

    for (int T = 0; T < NT; ++T) {
        const int cur = T & 1;
        if (T > 0) {
            __builtin_amdgcn_s_barrier();          // all waves done reading slot cur
            __builtin_amdgcn_sched_barrier(0);
        }
        // af(T): 8 global->reg loads, issued FIRST (in-order vmcnt queue)
        bf16x8 af[4][2];
        af[0][0] = *(const bf16x8*)aP0; af[0][1] = *(const bf16x8*)(aP0 + 32);
        af[1][0] = *(const bf16x8*)aP1; af[1][1] = *(const bf16x8*)(aP1 + 32);
        af[2][0] = *(const bf16x8*)aP2; af[2][1] = *(const bf16x8*)(aP2 + 32);
        af[3][0] = *(const bf16x8*)aP3; af[3][1] = *(const bf16x8*)(aP3 + 32);
        aP0 += 64; aP1 += 64; aP2 += 64; aP3 += 64;
        __builtin_amdgcn_sched_barrier(0);
        if (T + 1 < NT) {
            STAGE_B(cur ^ 1);                      // B(T+1): 4 newest
            __builtin_amdgcn_sched_barrier(0);
            asm volatile("s_waitcnt vmcnt(4)" ::: "memory");  // af(T)+B(T) retired
        } else {
            asm volatile("s_waitcnt vmcnt(0)" ::: "memory");
        }
        __builtin_amdgcn_s_barrier();              // all waves' B(T) writes visible
        __builtin_amdgcn_sched_barrier(0);

        const short* Bs_ = lds + cur * 8192;
        bf16x8 bfr[4][2];
#pragma unroll
        for (int n = 0; n < 4; ++n) {
            bfr[n][0] = *(const bf16x8*)&Bs_[boff0 + n * 1024];
            bfr[n][1] = *(const bf16x8*)&Bs_[boff1 + n * 1024];
        }
        __builtin_amdgcn_s_setprio(1);
#pragma unroll
        for (int m = 0; m < 4; ++m)
#pragma unroll
            for (int n = 0; n < 4; ++n)
#pragma unroll
                for (int ks = 0; ks < 2; ++ks)
                    acc[m][n] = __builtin_amdgcn_mfma_f32_16x16x32_bf16(af[m][ks], bfr[n][ks], acc[m][n], 0, 0, 0);
        __builtin_amdgcn_s_setprio(0);
    }
#undef STAGE_B

    // epilogue: C row = m0+wr*64+m*16+g*4+j, col = n0+wc*64+n*16+i15
    if (MODE == 0) {
#pragma unroll
        for (int m = 0; m < 4; ++m)
#pragma unroll
            for (int n = 0; n < 4; ++n) {
                int col = n0 + wc * 64 + n * 16 + i15;
                float bcol = bias[col];
#pragma unroll
                for (int j = 0; j < 4; ++j) {
                    int row = m0 + wr * 64 + m * 16 + g * 4 + j;
                    ((float*)Cout)[(size_t)row * N + col] = acc[m][n][j] + bcol;
                }
            }
    } else {
        const int sec = n0 >> 10;        // 0=q, 1=k, 2=v (128-blocks never straddle)
        if (sec < 2) {
            const float qs = (sec == 0) ? QSCALE : 1.0f;
            short* out = (short*)Cout;
#pragma unroll
            for (int m = 0; m < 4; ++m) {
#pragma unroll
                for (int pp = 0; pp < 2; ++pp) {     // pairs (n=pp, n=pp+2): cols d, d+32
                    int d = pp * 16 + i15;
                    int collo = n0 + wc * 64 + pp * 16 + i15;
                    float blo = bias[collo], bhi = bias[collo + 32];
#pragma unroll
                    for (int j = 0; j < 4; ++j) {
                        int row = m0 + wr * 64 + m * 16 + g * 4 + j;
                        int l = row & 2047;
                        float2 cs = *(const float2*)&tab[(l * 32 + d) * 2];
                        float x1 = acc[m][pp][j] + blo;
                        float x2 = acc[m][pp + 2][j] + bhi;
                        out[(size_t)row * 3072 + collo]      = f2bf((x1 * cs.x - x2 * cs.y) * qs);
                        out[(size_t)row * 3072 + collo + 32] = f2bf((x2 * cs.x + x1 * cs.y) * qs);
                    }
                }
            }
        } else {
            // v section: write V^T directly. VT[(b*16+h)*64 + d][l], 4 l per lane.
#pragma unroll
            for (int m = 0; m < 4; ++m) {
                int rbase = m0 + wr * 64 + m * 16 + g * 4;
                int lbase = rbase & 2047, bidx = rbase >> 11;
#pragma unroll
                for (int n = 0; n < 4; ++n) {
                    int vcol = (n0 - 2048) + wc * 64 + n * 16 + i15;
                    int h = vcol >> 6, d = vcol & 63;
                    float bb = bias[n0 + wc * 64 + n * 16 + i15];
                    union { unsigned w[2]; s16x4 v; } u;
                    u.w[0] = cvtpk(acc[m][n][0] + bb, acc[m][n][1] + bb);
                    u.w[1] = cvtpk(acc[m][n][2] + bb, acc[m][n][3] + bb);
                    *(s16x4*)&VTout[((size_t)(bidx * 16 + h) * 64 + d) * 2048 + lbase] = u.v;
                }
            }
        }
    }
}

// ---------------- flash attention: 32 q-rows per wave (unchanged R10) ----
__global__ __launch_bounds__(256, 4) void attn_kernel(const short* __restrict__ qkv,
                                                      const short* __restrict__ VT,
                                                      short* __restrict__ O) {
    __shared__ short Ks[2][64 * 64];
    __shared__ short Vs[2][64 * 64];
    int orig = blockIdx.x;
    int xcd = orig & 7, idx = orig >> 3;        // idx in [0,128)
    int bh = xcd * 8 + (idx >> 4), qt = idx & 15;
    int b = bh >> 4, h = bh & 15;
    int tid = threadIdx.x, lane = tid & 63, wave = tid >> 6;
    int i15 = lane & 15, g = lane >> 4;
    int q0 = qt * 128;

    size_t qbase = (size_t)(b * 2048 + q0 + wave * 32);
    bf16x8 qf[2][2];
#pragma unroll
    for (int qg = 0; qg < 2; ++qg) {
        qf[qg][0] = *(const bf16x8*)&qkv[(qbase + qg * 16 + i15) * 3072 + h * 64 + 0  + g * 8];
        qf[qg][1] = *(const bf16x8*)&qkv[(qbase + qg * 16 + i15) * 3072 + h * 64 + 32 + g * 8];
    }

    bf16x8 onesf;
#pragma unroll
    for (int e = 0; e < 8; ++e) onesf[e] = (short)0x3F80;   // bf16 1.0

    const int srow = tid >> 3;
    const int ss8 = (tid & 7) ^ (srow & 7);
    const int pr0 = (srow & 0x23) | ((srow & 0x10) >> 2) | ((srow & 0x0C) << 1);
    const int sr1 = srow + 32;
    const int pr1 = (sr1 & 0x23) | ((sr1 & 0x10) >> 2) | ((sr1 & 0x0C) << 1);
    const short* kb_ = qkv + (size_t)(b * 2048) * 3072 + 1024 + h * 64 + ss8 * 8;
    const short* kp0 = kb_ + (size_t)pr0 * 3072;
    const short* kp1 = kb_ + (size_t)pr1 * 3072;
    const short* vb_ = VT + (size_t)bh * 64 * 2048 + ss8 * 8;
    const short* vp0 = vb_ + (size_t)srow * 2048;
    const short* vp1 = vb_ + (size_t)sr1 * 2048;

    const int xr3 = i15 & 3, xb2 = (i15 >> 2) & 1;
    const int cLo = g ^ xr3;
    const int o0 = i15 * 64 + (xb2 * 4 + cLo) * 8;
    const int o1 = i15 * 64 + ((1 ^ xb2) * 4 + cLo) * 8;

    f32x4 acc_o[2][4] = {};
    f32x4 acc_l[2] = {};

#define STAGE(bk, bv)                                        \
    do {                                                     \
        gld_lds16(kp0, (bk) + wave * 512);                   \
        gld_lds16(kp1, (bk) + 2048 + wave * 512);            \
        gld_lds16(vp0, (bv) + wave * 512);                   \
        gld_lds16(vp1, (bv) + 2048 + wave * 512);            \
        kp0 += (size_t)64 * 3072; kp1 += (size_t)64 * 3072;  \
        vp0 += 64; vp1 += 64;                                \
    } while (0)

    STAGE(Ks[0], Vs[0]);

    for (int t = 0; t < 32; ++t) {
        const int cur = t & 1;
        if (t > 0) {
            __builtin_amdgcn_s_barrier();
            __builtin_amdgcn_sched_barrier(0);
        }
        if (t + 1 < 32) {
            STAGE(Ks[cur ^ 1], Vs[cur ^ 1]);
            asm volatile("s_waitcnt vmcnt(4)" ::: "memory");
        } else {
            asm volatile("s_waitcnt vmcnt(0)" ::: "memory");
        }
        __builtin_amdgcn_s_barrier();
        __builtin_amdgcn_sched_barrier(0);

        const short* ks = Ks[cur];
        const short* vs = Vs[cur];

        f32x4 sa[2][4] = {};
        __builtin_amdgcn_s_setprio(1);
#pragma unroll
        for (int kb = 0; kb < 2; ++kb) {
            const int ko = kb ? o1 : o0;
            bf16x8 kf[4];
#pragma unroll
            for (int jb = 0; jb < 4; ++jb) kf[jb] = *(const bf16x8*)&ks[ko + jb * 1024];
#pragma unroll
            for (int qg = 0; qg < 2; ++qg)
#pragma unroll
                for (int jb = 0; jb < 4; ++jb)
                    sa[qg][jb] = __builtin_amdgcn_mfma_f32_16x16x32_bf16(kf[jb], qf[qg][kb], sa[qg][jb], 0, 0, 0);
        }
        __builtin_amdgcn_s_setprio(0);

        bf16x8 pf[2][2];
#pragma unroll
        for (int qg = 0; qg < 2; ++qg) {
            float p[4][4];
#pragma unroll
            for (int jb = 0; jb < 4; ++jb)
#pragma unroll
                for (int r = 0; r < 4; ++r)
                    p[jb][r] = __builtin_amdgcn_exp2f(sa[qg][jb][r]);
#pragma unroll
            for (int kb = 0; kb < 2; ++kb) {
                union { unsigned w[4]; bf16x8 v; } u;
                u.w[0] = cvtpk(p[2 * kb][0],     p[2 * kb][1]);
                u.w[1] = cvtpk(p[2 * kb][2],     p[2 * kb][3]);
                u.w[2] = cvtpk(p[2 * kb + 1][0], p[2 * kb + 1][1]);
                u.w[3] = cvtpk(p[2 * kb + 1][2], p[2 * kb + 1][3]);
                pf[qg][kb] = u.v;
            }
        }

        __builtin_amdgcn_s_setprio(1);
#pragma unroll
        for (int db = 0; db < 4; ++db) {
#pragma unroll
            for (int kb = 0; kb < 2; ++kb) {
                bf16x8 vf = *(const bf16x8*)&vs[(kb ? o1 : o0) + db * 1024];
#pragma unroll
                for (int qg = 0; qg < 2; ++qg)
                    acc_o[qg][db] = __builtin_amdgcn_mfma_f32_16x16x32_bf16(pf[qg][kb], vf, acc_o[qg][db], 0, 0, 0);
            }
        }
#pragma unroll
        for (int qg = 0; qg < 2; ++qg) {
            acc_l[qg] = __builtin_amdgcn_mfma_f32_16x16x32_bf16(pf[qg][0], onesf, acc_l[qg], 0, 0, 0);
            acc_l[qg] = __builtin_amdgcn_mfma_f32_16x16x32_bf16(pf[qg][1], onesf, acc_l[qg], 0, 0, 0);
        }
        __builtin_amdgcn_s_setprio(0);
    }
#undef STAGE

#pragma unroll
    for (int qg = 0; qg < 2; ++qg) {
        float linv4[4];
#pragma unroll
        for (int r = 0; r < 4; ++r) linv4[r] = 1.f / acc_l[qg][r];
#pragma unroll
        for (int db = 0; db < 4; ++db) {
            int ocol = h * 64 + db * 16 + i15;
#pragma unroll
            for (int r = 0; r < 4; ++r) {
                size_t orow = qbase + qg * 16 + g * 4 + r;
                O[orow * 1024 + ocol] = f2bf(acc_o[qg][db][r] * linv4[r]);
            }
        }
    }
}

extern "C" void kernel_launch(void* const* d_in, const int* in_sizes, int n_in,
                              void* d_out, int out_size, void* d_ws, size_t ws_size,
                              hipStream_t stream) {
    const float* x     = (const float*)d_in[0];
    const float* w_qkv = (const float*)d_in[1];
    const float* b_qkv = (const float*)d_in[2];
    const float* w_out = (const float*)d_in[3];
    const float* b_out = (const float*)d_in[4];

    char* ws = (char*)d_ws;
    short* qkvb = (short*)(ws);                 // 8192*3072*2  = 50331648 (v sec unused)
    short* xb   = (short*)(ws + 50331648);      // 8192*1024*2  = 16777216 (reused as O)
    short* wqb  = (short*)(ws + 67108864);      // 3072*1024*2  =  6291456
    short* wob  = (short*)(ws + 73400320);      // 1024*1024*2  =  2097152
    short* VT   = (short*)(ws + 75497472);      // 64*64*2048*2 = 16777216
    float* rt   = (float*)(ws + 92274688);      // 2048*32*2*4  =   524288
    short* Ob   = xb;                           // reuse x_bf16 region for attn output

    prep_kernel<<<6400, 256, 0, stream>>>(x, w_qkv, w_out, xb, wqb, wob, rt);

    gemm_bt<1><<<dim3(24, 64), 256, 0, stream>>>(xb, wqb, b_qkv, qkvb, VT, rt, 8192, 3072, 1024);
    attn_kernel<<<1024, 256, 0, stream>>>(qkvb, VT, Ob);
    gemm_bt<0><<<dim3(8, 64), 256, 0, stream>>>(Ob, wob, b_out, d_out, nullptr, nullptr, 8192, 1024, 1024);
}

// Round 16
// 174.299 us; speedup vs baseline: 2.2948x; 1.3397x over previous
//
#include <hip/hip_runtime.h>
#include <stdint.h>

typedef __attribute__((ext_vector_type(4))) float f32x4;
typedef __attribute__((ext_vector_type(8))) short bf16x8;
typedef __attribute__((ext_vector_type(4))) short s16x4;
typedef __attribute__((ext_vector_type(4))) float fp32x4;

#define QSCALE 0.18033688f   // 0.125 * log2(e): scores exit QK^T in log2 domain

__device__ __forceinline__ short f2bf(float f) {
    union { float f; unsigned u; } v; v.f = f;
    unsigned u = v.u;
    unsigned r = u + 0x7fffu + ((u >> 16) & 1u);
    return (short)(r >> 16);
}
// packed bf16 convert (RNE), lo = a, hi = b
__device__ __forceinline__ unsigned cvtpk(float a, float b) {
    unsigned r;
    asm("v_cvt_pk_bf16_f32 %0, %1, %2" : "=v"(r) : "v"(a), "v"(b));
    return r;
}

// async global->LDS, 16B per lane. dest = wave-uniform base + lane*16.
__device__ __forceinline__ void gld_lds16(const void* g, void* l) {
    __builtin_amdgcn_global_load_lds(
        (const __attribute__((address_space(1))) unsigned int*)(uintptr_t)g,
        (__attribute__((address_space(3))) unsigned int*)(uintptr_t)l,
        16, 0, 0);
}

// ---------------- fused prep: all casts + RoPE table in ONE launch --------
__global__ __launch_bounds__(256) void prep_kernel(const float* __restrict__ x,
                                                   const float* __restrict__ wq,
                                                   const float* __restrict__ wo,
                                                   short* __restrict__ xb,
                                                   short* __restrict__ wqb,
                                                   short* __restrict__ wob,
                                                   float* __restrict__ tab) {
    int bid = blockIdx.x, tid = threadIdx.x;
    if (bid < 6144) {
        const float* in; short* out; int base;
        if (bid < 4096)      { in = x;  out = xb;  base = bid; }
        else if (bid < 5632) { in = wq; out = wqb; base = bid - 4096; }
        else                 { in = wo; out = wob; base = bid - 5632; }
        int idx = (base * 256 + tid) * 8;
        fp32x4 a = *(const fp32x4*)&in[idx];
        fp32x4 b = *(const fp32x4*)&in[idx + 4];
        union { unsigned w[4]; bf16x8 v; } u;
        u.w[0] = cvtpk(a[0], a[1]); u.w[1] = cvtpk(a[2], a[3]);
        u.w[2] = cvtpk(b[0], b[1]); u.w[3] = cvtpk(b[2], b[3]);
        *(bf16x8*)&out[idx] = u.v;
    } else {
        int idx = (bid - 6144) * 256 + tid;   // 65536
        int l = idx >> 5, d = idx & 31;
        float inv = expf(-(float)d / 32.f * logf(10000.f));
        float ang = (float)l * inv;
        tab[idx * 2 + 0] = cosf(ang);
        tab[idx * 2 + 1] = sinf(ang);
    }
}

// ---------------- GEMM: C[M,N] = A[M,K]*B[N,K]^T + bias, bf16 in ----------
// BM=BN=128, BK=32, 4 waves (2x2), per-wave 64x64 output, 256 threads.
// PAIR-INTERLEAVED LDS (HW-verified conflict-free in R13: bank-conflict=0):
// row-pairs share one 128B line -> 8 slot-columns -> conflict-free b128.
// Line p holds rows {2p,2p+1}; slot s stores (parity=s0>>2, kgrp=s0&3),
// s = s0 ^ (p&7). 2-slot ring = 32 KB; VGPR ~90 ((256,2) bounds — R13's
// (256,5) forced 48 VGPR and spilled acc to scratch, 494 MB writes) ->
// 4 blocks/CU = 16 waves/CU, the attn-measured high-occupancy regime.
// Window (x32): {barrier; STAGE 4 loads; vmcnt(4); barrier; 8 ds_read_b128
// + 16 MFMA (setprio)}. XCD N-PARTITION: xcd=bid&7 owns fixed n-chunk.
// MODE 0: fp32 out + bias. MODE 1: fused QKV epilogue (RoPE q/k, +QSCALE on
// q, bf16 qkv; v section written transposed to VT[bh][d][L]).
template<int MODE>
__global__ __launch_bounds__(256, 2)
void gemm_bt(const short* __restrict__ A,
             const short* __restrict__ B,
             const float* __restrict__ bias,
             void* __restrict__ Cout,
             short* __restrict__ VTout,
             const float* __restrict__ tab,
             int M, int N, int K) {
    __shared__ short lds[2 * 8192];   // slot = A[64 lines x 128B] + B same = 16 KB
    const int tid = threadIdx.x;
    const int lane = tid & 63, wave = tid >> 6;
    const int i15 = lane & 15, g = lane >> 4;
    const int wr = wave >> 1, wc = wave & 1;

    // XCD n-partition: xcd = bid&7 owns n-chunk of nbx/8 n-blocks.
    const int nbx = gridDim.x;
    int bid = blockIdx.y * nbx + blockIdx.x;
    const int xcd = bid & 7, idx = bid >> 3;
    const int nchunk = nbx >> 3;
    const int n0 = (xcd * nchunk + (idx % nchunk)) * 128;
    const int m0 = (idx / nchunk) * 128;

    // LDS read bases (pair-interleave): line p = wr*32 + m*8 + (i15>>1),
    // slot sr = ((i15&1)*4 + g) ^ p&7; (m*8)&7==0 so sr is m-invariant.
    const int pb = i15 >> 1;
    const int sr = (((i15 & 1) << 2) | g) ^ pb;
    const int aoff = (wr * 32 + pb) * 64 + sr * 8;   // shorts; af[m] = +m*512
    const int boff = (wc * 32 + pb) * 64 + sr * 8;

    // staging sources (inverse pair-swizzle). Chunk i covers lines
    // p = i*32 + (t>>3); stored slot t&7 holds s0 = (t&7)^(p&7):
    // global row = i*64 + 2*(t>>3) + (s0>>2), k-grp = s0&3.
    const int s0 = (tid & 7) ^ ((tid >> 3) & 7);
    const int row0 = 2 * (tid >> 3) + (s0 >> 2);
    const int kc = (s0 & 3) * 8;
    const short* pA0 = A + (size_t)(m0 + row0) * K + kc;
    const short* pA1 = A + (size_t)(m0 + row0 + 64) * K + kc;
    const short* pB0 = B + (size_t)(n0 + row0) * K + kc;
    const short* pB1 = B + (size_t)(n0 + row0 + 64) * K + kc;

    // dest: wave-uniform base (HW adds lane*16B). Chunk i at slot*8192 +
    // i*2048 + wave*512 shorts; B at +4096.
#define STAGE(slot)                                                   \
    do {                                                              \
        gld_lds16(pA0, lds + (slot) * 8192 + 0 * 2048 + wave * 512);  \
        gld_lds16(pA1, lds + (slot) * 8192 + 1 * 2048 + wave * 512);  \
        gld_lds16(pB0, lds + (slot) * 8192 + 4096 + 0 * 2048 + wave * 512); \
        gld_lds16(pB1, lds + (slot) * 8192 + 4096 + 1 * 2048 + wave * 512); \
        pA0 += 32; pA1 += 32; pB0 += 32; pB1 += 32;                   \
    } while (0)

    STAGE(0);

    f32x4 acc[4][4] = {};
    const int NT = K >> 5;   // 32 windows for K=1024

    for (int T = 0; T < NT; ++T) {
        const int cur = T & 1;
        if (T > 0) {
            __builtin_amdgcn_s_barrier();          // all waves done reading slot cur
            __builtin_amdgcn_sched_barrier(0);
        }
        if (T + 1 < NT) {
            STAGE(cur ^ 1);                        // 4 loads for tile T+1
            asm volatile("s_waitcnt vmcnt(4)" ::: "memory");  // tile T landed
        } else {
            asm volatile("s_waitcnt vmcnt(0)" ::: "memory");
        }
        __builtin_amdgcn_s_barrier();
        __builtin_amdgcn_sched_barrier(0);

        const short* As_ = lds + cur * 8192;
        const short* Bs_ = As_ + 4096;
        bf16x8 af[4], bfr[4];
#pragma unroll
        for (int m = 0; m < 4; ++m) af[m] = *(const bf16x8*)&As_[aoff + m * 512];
#pragma unroll
        for (int n = 0; n < 4; ++n) bfr[n] = *(const bf16x8*)&Bs_[boff + n * 512];
        __builtin_amdgcn_s_setprio(1);
#pragma unroll
        for (int m = 0; m < 4; ++m)
#pragma unroll
            for (int n = 0; n < 4; ++n)
                acc[m][n] = __builtin_amdgcn_mfma_f32_16x16x32_bf16(af[m], bfr[n], acc[m][n], 0, 0, 0);
        __builtin_amdgcn_s_setprio(0);
    }
#undef STAGE

    // epilogue: C row = m0+wr*64+m*16+g*4+j, col = n0+wc*64+n*16+i15
    if (MODE == 0) {
#pragma unroll
        for (int m = 0; m < 4; ++m)
#pragma unroll
            for (int n = 0; n < 4; ++n) {
                int col = n0 + wc * 64 + n * 16 + i15;
                float bcol = bias[col];
#pragma unroll
                for (int j = 0; j < 4; ++j) {
                    int row = m0 + wr * 64 + m * 16 + g * 4 + j;
                    ((float*)Cout)[(size_t)row * N + col] = acc[m][n][j] + bcol;
                }
            }
    } else {
        const int sec = n0 >> 10;        // 0=q, 1=k, 2=v (128-blocks never straddle)
        if (sec < 2) {
            const float qs = (sec == 0) ? QSCALE : 1.0f;
            short* out = (short*)Cout;
#pragma unroll
            for (int m = 0; m < 4; ++m) {
#pragma unroll
                for (int pp = 0; pp < 2; ++pp) {     // pairs (n=pp, n=pp+2): cols d, d+32
                    int d = pp * 16 + i15;
                    int collo = n0 + wc * 64 + pp * 16 + i15;
                    float blo = bias[collo], bhi = bias[collo + 32];
#pragma unroll
                    for (int j = 0; j < 4; ++j) {
                        int row = m0 + wr * 64 + m * 16 + g * 4 + j;
                        int l = row & 2047;
                        float2 cs = *(const float2*)&tab[(l * 32 + d) * 2];
                        float x1 = acc[m][pp][j] + blo;
                        float x2 = acc[m][pp + 2][j] + bhi;
                        out[(size_t)row * 3072 + collo]      = f2bf((x1 * cs.x - x2 * cs.y) * qs);
                        out[(size_t)row * 3072 + collo + 32] = f2bf((x2 * cs.x + x1 * cs.y) * qs);
                    }
                }
            }
        } else {
            // v section: write V^T directly. VT[(b*16+h)*64 + d][l], 4 l per lane.
#pragma unroll
            for (int m = 0; m < 4; ++m) {
                int rbase = m0 + wr * 64 + m * 16 + g * 4;
                int lbase = rbase & 2047, bidx = rbase >> 11;
#pragma unroll
                for (int n = 0; n < 4; ++n) {
                    int vcol = (n0 - 2048) + wc * 64 + n * 16 + i15;
                    int h = vcol >> 6, d = vcol & 63;
                    float bb = bias[n0 + wc * 64 + n * 16 + i15];
                    union { unsigned w[2]; s16x4 v; } u;
                    u.w[0] = cvtpk(acc[m][n][0] + bb, acc[m][n][1] + bb);
                    u.w[1] = cvtpk(acc[m][n][2] + bb, acc[m][n][3] + bb);
                    *(s16x4*)&VTout[((size_t)(bidx * 16 + h) * 64 + d) * 2048 + lbase] = u.v;
                }
            }
        }
    }
}

// ---------------- flash attention: 32 q-rows per wave (unchanged R10) ----
__global__ __launch_bounds__(256, 4) void attn_kernel(const short* __restrict__ qkv,
                                                      const short* __restrict__ VT,
                                                      short* __restrict__ O) {
    __shared__ short Ks[2][64 * 64];
    __shared__ short Vs[2][64 * 64];
    int orig = blockIdx.x;
    int xcd = orig & 7, idx = orig >> 3;        // idx in [0,128)
    int bh = xcd * 8 + (idx >> 4), qt = idx & 15;
    int b = bh >> 4, h = bh & 15;
    int tid = threadIdx.x, lane = tid & 63, wave = tid >> 6;
    int i15 = lane & 15, g = lane >> 4;
    int q0 = qt * 128;

    size_t qbase = (size_t)(b * 2048 + q0 + wave * 32);
    bf16x8 qf[2][2];
#pragma unroll
    for (int qg = 0; qg < 2; ++qg) {
        qf[qg][0] = *(const bf16x8*)&qkv[(qbase + qg * 16 + i15) * 3072 + h * 64 + 0  + g * 8];
        qf[qg][1] = *(const bf16x8*)&qkv[(qbase + qg * 16 + i15) * 3072 + h * 64 + 32 + g * 8];
    }

    bf16x8 onesf;
#pragma unroll
    for (int e = 0; e < 8; ++e) onesf[e] = (short)0x3F80;   // bf16 1.0

    const int srow = tid >> 3;
    const int ss8 = (tid & 7) ^ (srow & 7);
    const int pr0 = (srow & 0x23) | ((srow & 0x10) >> 2) | ((srow & 0x0C) << 1);
    const int sr1 = srow + 32;
    const int pr1 = (sr1 & 0x23) | ((sr1 & 0x10) >> 2) | ((sr1 & 0x0C) << 1);
    const short* kb_ = qkv + (size_t)(b * 2048) * 3072 + 1024 + h * 64 + ss8 * 8;
    const short* kp0 = kb_ + (size_t)pr0 * 3072;
    const short* kp1 = kb_ + (size_t)pr1 * 3072;
    const short* vb_ = VT + (size_t)bh * 64 * 2048 + ss8 * 8;
    const short* vp0 = vb_ + (size_t)srow * 2048;
    const short* vp1 = vb_ + (size_t)sr1 * 2048;

    const int xr3 = i15 & 3, xb2 = (i15 >> 2) & 1;
    const int cLo = g ^ xr3;
    const int o0 = i15 * 64 + (xb2 * 4 + cLo) * 8;
    const int o1 = i15 * 64 + ((1 ^ xb2) * 4 + cLo) * 8;

    f32x4 acc_o[2][4] = {};
    f32x4 acc_l[2] = {};

#define STAGE(bk, bv)                                        \
    do {                                                     \
        gld_lds16(kp0, (bk) + wave * 512);                   \
        gld_lds16(kp1, (bk) + 2048 + wave * 512);            \
        gld_lds16(vp0, (bv) + wave * 512);                   \
        gld_lds16(vp1, (bv) + 2048 + wave * 512);            \
        kp0 += (size_t)64 * 3072; kp1 += (size_t)64 * 3072;  \
        vp0 += 64; vp1 += 64;                                \
    } while (0)

    STAGE(Ks[0], Vs[0]);

    for (int t = 0; t < 32; ++t) {
        const int cur = t & 1;
        if (t > 0) {
            __builtin_amdgcn_s_barrier();
            __builtin_amdgcn_sched_barrier(0);
        }
        if (t + 1 < 32) {
            STAGE(Ks[cur ^ 1], Vs[cur ^ 1]);
            asm volatile("s_waitcnt vmcnt(4)" ::: "memory");
        } else {
            asm volatile("s_waitcnt vmcnt(0)" ::: "memory");
        }
        __builtin_amdgcn_s_barrier();
        __builtin_amdgcn_sched_barrier(0);

        const short* ks = Ks[cur];
        const short* vs = Vs[cur];

        f32x4 sa[2][4] = {};
        __builtin_amdgcn_s_setprio(1);
#pragma unroll
        for (int kb = 0; kb < 2; ++kb) {
            const int ko = kb ? o1 : o0;
            bf16x8 kf[4];
#pragma unroll
            for (int jb = 0; jb < 4; ++jb) kf[jb] = *(const bf16x8*)&ks[ko + jb * 1024];
#pragma unroll
            for (int qg = 0; qg < 2; ++qg)
#pragma unroll
                for (int jb = 0; jb < 4; ++jb)
                    sa[qg][jb] = __builtin_amdgcn_mfma_f32_16x16x32_bf16(kf[jb], qf[qg][kb], sa[qg][jb], 0, 0, 0);
        }
        __builtin_amdgcn_s_setprio(0);

        bf16x8 pf[2][2];
#pragma unroll
        for (int qg = 0; qg < 2; ++qg) {
            float p[4][4];
#pragma unroll
            for (int jb = 0; jb < 4; ++jb)
#pragma unroll
                for (int r = 0; r < 4; ++r)
                    p[jb][r] = __builtin_amdgcn_exp2f(sa[qg][jb][r]);
#pragma unroll
            for (int kb = 0; kb < 2; ++kb) {
                union { unsigned w[4]; bf16x8 v; } u;
                u.w[0] = cvtpk(p[2 * kb][0],     p[2 * kb][1]);
                u.w[1] = cvtpk(p[2 * kb][2],     p[2 * kb][3]);
                u.w[2] = cvtpk(p[2 * kb + 1][0], p[2 * kb + 1][1]);
                u.w[3] = cvtpk(p[2 * kb + 1][2], p[2 * kb + 1][3]);
                pf[qg][kb] = u.v;
            }
        }

        __builtin_amdgcn_s_setprio(1);
#pragma unroll
        for (int db = 0; db < 4; ++db) {
#pragma unroll
            for (int kb = 0; kb < 2; ++kb) {
                bf16x8 vf = *(const bf16x8*)&vs[(kb ? o1 : o0) + db * 1024];
#pragma unroll
                for (int qg = 0; qg < 2; ++qg)
                    acc_o[qg][db] = __builtin_amdgcn_mfma_f32_16x16x32_bf16(pf[qg][kb], vf, acc_o[qg][db], 0, 0, 0);
            }
        }
#pragma unroll
        for (int qg = 0; qg < 2; ++qg) {
            acc_l[qg] = __builtin_amdgcn_mfma_f32_16x16x32_bf16(pf[qg][0], onesf, acc_l[qg], 0, 0, 0);
            acc_l[qg] = __builtin_amdgcn_mfma_f32_16x16x32_bf16(pf[qg][1], onesf, acc_l[qg], 0, 0, 0);
        }
        __builtin_amdgcn_s_setprio(0);
    }
#undef STAGE

#pragma unroll
    for (int qg = 0; qg < 2; ++qg) {
        float linv4[4];
#pragma unroll
        for (int r = 0; r < 4; ++r) linv4[r] = 1.f / acc_l[qg][r];
#pragma unroll
        for (int db = 0; db < 4; ++db) {
            int ocol = h * 64 + db * 16 + i15;
#pragma unroll
            for (int r = 0; r < 4; ++r) {
                size_t orow = qbase + qg * 16 + g * 4 + r;
                O[orow * 1024 + ocol] = f2bf(acc_o[qg][db][r] * linv4[r]);
            }
        }
    }
}

extern "C" void kernel_launch(void* const* d_in, const int* in_sizes, int n_in,
                              void* d_out, int out_size, void* d_ws, size_t ws_size,
                              hipStream_t stream) {
    const float* x     = (const float*)d_in[0];
    const float* w_qkv = (const float*)d_in[1];
    const float* b_qkv = (const float*)d_in[2];
    const float* w_out = (const float*)d_in[3];
    const float* b_out = (const float*)d_in[4];

    char* ws = (char*)d_ws;
    short* qkvb = (short*)(ws);                 // 8192*3072*2  = 50331648 (v sec unused)
    short* xb   = (short*)(ws + 50331648);      // 8192*1024*2  = 16777216 (reused as O)
    short* wqb  = (short*)(ws + 67108864);      // 3072*1024*2  =  6291456
    short* wob  = (short*)(ws + 73400320);      // 1024*1024*2  =  2097152
    short* VT   = (short*)(ws + 75497472);      // 64*64*2048*2 = 16777216
    float* rt   = (float*)(ws + 92274688);      // 2048*32*2*4  =   524288
    short* Ob   = xb;                           // reuse x_bf16 region for attn output

    prep_kernel<<<6400, 256, 0, stream>>>(x, w_qkv, w_out, xb, wqb, wob, rt);

    gemm_bt<1><<<dim3(24, 64), 256, 0, stream>>>(xb, wqb, b_qkv, qkvb, VT, rt, 8192, 3072, 1024);
    attn_kernel<<<1024, 256, 0, stream>>>(qkvb, VT, Ob);
    gemm_bt<0><<<dim3(8, 64), 256, 0, stream>>>(Ob, wob, b_out, d_out, nullptr, nullptr, 8192, 1024, 1024);
}

// Round 17
// 173.320 us; speedup vs baseline: 2.3078x; 1.0057x over previous
//
#include <hip/hip_runtime.h>
#include <stdint.h>

typedef __attribute__((ext_vector_type(4))) float f32x4;
typedef __attribute__((ext_vector_type(8))) short bf16x8;
typedef __attribute__((ext_vector_type(4))) short s16x4;
typedef __attribute__((ext_vector_type(4))) float fp32x4;

#define QSCALE 0.18033688f   // 0.125 * log2(e): scores exit QK^T in log2 domain

__device__ __forceinline__ short f2bf(float f) {
    union { float f; unsigned u; } v; v.f = f;
    unsigned u = v.u;
    unsigned r = u + 0x7fffu + ((u >> 16) & 1u);
    return (short)(r >> 16);
}
// packed bf16 convert (RNE), lo = a, hi = b
__device__ __forceinline__ unsigned cvtpk(float a, float b) {
    unsigned r;
    asm("v_cvt_pk_bf16_f32 %0, %1, %2" : "=v"(r) : "v"(a), "v"(b));
    return r;
}

// async global->LDS, 16B per lane. dest = wave-uniform base + lane*16.
__device__ __forceinline__ void gld_lds16(const void* g, void* l) {
    __builtin_amdgcn_global_load_lds(
        (const __attribute__((address_space(1))) unsigned int*)(uintptr_t)g,
        (__attribute__((address_space(3))) unsigned int*)(uintptr_t)l,
        16, 0, 0);
}

// ---------------- fused prep: casts + RoPE table in ONE launch ------------
// x is cast AND PACKED into MFMA-fragment order: chunk (mt,kt) = 64 lanes x
// 16B, lane g*16+i15 holds x[mt*16+i15][kt*32+g*8 .. +7]. The QKV GEMM then
// loads A-fragments global->VGPR fully coalesced (no LDS for A).
__global__ __launch_bounds__(256) void prep_kernel(const float* __restrict__ x,
                                                   const float* __restrict__ wq,
                                                   const float* __restrict__ wo,
                                                   short* __restrict__ xp,
                                                   short* __restrict__ wqb,
                                                   short* __restrict__ wob,
                                                   float* __restrict__ tab) {
    int bid = blockIdx.x, tid = threadIdx.x;
    if (bid < 4096) {                       // x: cast + fragment-pack
        int idx = (bid * 256 + tid) * 8;    // element index into x
        fp32x4 a = *(const fp32x4*)&x[idx];
        fp32x4 b = *(const fp32x4*)&x[idx + 4];
        union { unsigned w[4]; bf16x8 v; } u;
        u.w[0] = cvtpk(a[0], a[1]); u.w[1] = cvtpk(a[2], a[3]);
        u.w[2] = cvtpk(b[0], b[1]); u.w[3] = cvtpk(b[2], b[3]);
        int m = idx >> 10, k0 = idx & 1023;
        int mt = m >> 4, i15 = m & 15;
        int kt = k0 >> 5, g = (k0 >> 3) & 3;
        *(bf16x8*)&xp[(size_t)((mt * 32 + kt) * 64 + g * 16 + i15) * 8] = u.v;
    } else if (bid < 6144) {                // weight casts (row-major)
        const float* in; short* out; int base;
        if (bid < 5632) { in = wq; out = wqb; base = bid - 4096; }
        else            { in = wo; out = wob; base = bid - 5632; }
        int idx = (base * 256 + tid) * 8;
        fp32x4 a = *(const fp32x4*)&in[idx];
        fp32x4 b = *(const fp32x4*)&in[idx + 4];
        union { unsigned w[4]; bf16x8 v; } u;
        u.w[0] = cvtpk(a[0], a[1]); u.w[1] = cvtpk(a[2], a[3]);
        u.w[2] = cvtpk(b[0], b[1]); u.w[3] = cvtpk(b[2], b[3]);
        *(bf16x8*)&out[idx] = u.v;
    } else {
        int idx = (bid - 6144) * 256 + tid;   // 65536
        int l = idx >> 5, d = idx & 31;
        float inv = expf(-(float)d / 32.f * logf(10000.f));
        float ang = (float)l * inv;
        tab[idx * 2 + 0] = cosf(ang);
        tab[idx * 2 + 1] = sinf(ang);
    }
}

// ---------------- QKV GEMM: packed-A (global->reg), B via LDS -------------
// BM=BN=128, BK=64, 4 waves (2x2), per-wave 64x64. A-fragments loaded direct
// from packed xp (coalesced 1KB/instr), double-buffered in registers, issued
// one window ahead. B staged through 2-slot LDS (16KB/slot) with R10's
// proven swizzle. LDS traffic per window halves vs A+B staging (the pipe
// arithmetic binder). Window: {barrier; issue A(T+1) 8 + stage B(T+1) 4;
// vmcnt(12) [A(T),B(T) retired]; barrier; 8 ds_read + 32 MFMA (setprio)}.
// Unrolled x2 so the af register double-buffer has static indices (rule #20).
// Fused epilogue: RoPE q/k (+QSCALE on q) -> bf16 qkv; v -> VT[bh][d][L].
__global__ __launch_bounds__(256) void gemm_qkv(const short* __restrict__ Ap,
                                                const short* __restrict__ B,
                                                const float* __restrict__ bias,
                                                short* __restrict__ out,
                                                short* __restrict__ VTout,
                                                const float* __restrict__ tab) {
    constexpr int K = 1024, N = 3072, NT = 16;
    __shared__ short lds[2 * 8192];   // 2 slots x B[128x64] = 32 KB
    const int tid = threadIdx.x;
    const int lane = tid & 63, wave = tid >> 6;
    const int i15 = lane & 15, g = lane >> 4;
    const int wr = wave >> 1, wc = wave & 1;

    // R10 chunk-swizzle (m-chunks per XCD -> A-panel L2 reuse)
    const int nbx = gridDim.x;
    const int nwg = nbx * gridDim.y;
    int bid = blockIdx.y * nbx + blockIdx.x;
    int sw = (bid & 7) * (nwg >> 3) + (bid >> 3);
    const int m0 = (sw / nbx) * 128;
    const int n0 = (sw % nbx) * 128;

    // B LDS read bases (R10 split-XOR swizzle)
    const int xr3 = i15 & 3, xb2 = (i15 >> 2) & 1;
    const int cLo = g ^ xr3;
    const int boff0 = (wc * 64 + i15) * 64 + (xb2 * 4 + cLo) * 8;
    const int boff1 = (wc * 64 + i15) * 64 + ((1 ^ xb2) * 4 + cLo) * 8;

    // B staging (R10): thread covers rows r*32 + (tid>>3), col-grp tid&7
    const int srow = tid >> 3;
    const int ss = (tid & 7) ^ (srow & 7);
    const short* b0 = B + (size_t)(n0 + srow) * K + ss * 8;
    const short* b1 = b0 + (size_t)32 * K;
    const short* b2 = b0 + (size_t)64 * K;
    const short* b3 = b0 + (size_t)96 * K;

#define STAGE_B(slot)                                                 \
    do {                                                              \
        gld_lds16(b0, lds + (slot) * 8192 + 0 * 2048 + wave * 512);   \
        gld_lds16(b1, lds + (slot) * 8192 + 1 * 2048 + wave * 512);   \
        gld_lds16(b2, lds + (slot) * 8192 + 2 * 2048 + wave * 512);   \
        gld_lds16(b3, lds + (slot) * 8192 + 3 * 2048 + wave * 512);   \
        b0 += 64; b1 += 64; b2 += 64; b3 += 64;                       \
    } while (0)

    // packed-A pointer: chunk (mt,kt) at (mt*32+kt)*512 shorts; lane offset *8.
    // mt for af[m] = (m0>>4) + wr*4 + m; kt advances 2 per window.
    const short* aP = Ap + (size_t)((m0 >> 4) + wr * 4) * 16384 + lane * 8;

#define LOAD_A(dst)                                                    \
    do {                                                               \
        dst[0][0] = *(const bf16x8*)(aP + 0 * 16384);                  \
        dst[0][1] = *(const bf16x8*)(aP + 0 * 16384 + 512);            \
        dst[1][0] = *(const bf16x8*)(aP + 1 * 16384);                  \
        dst[1][1] = *(const bf16x8*)(aP + 1 * 16384 + 512);            \
        dst[2][0] = *(const bf16x8*)(aP + 2 * 16384);                  \
        dst[2][1] = *(const bf16x8*)(aP + 2 * 16384 + 512);            \
        dst[3][0] = *(const bf16x8*)(aP + 3 * 16384);                  \
        dst[3][1] = *(const bf16x8*)(aP + 3 * 16384 + 512);            \
        aP += 1024;                                                    \
    } while (0)

#define COMPUTE(afS, slot)                                             \
    do {                                                               \
        const short* Bs_ = lds + (slot) * 8192;                        \
        bf16x8 bfr[4][2];                                              \
        _Pragma("unroll")                                              \
        for (int n = 0; n < 4; ++n) {                                  \
            bfr[n][0] = *(const bf16x8*)&Bs_[boff0 + n * 1024];        \
            bfr[n][1] = *(const bf16x8*)&Bs_[boff1 + n * 1024];        \
        }                                                              \
        __builtin_amdgcn_s_setprio(1);                                 \
        _Pragma("unroll")                                              \
        for (int m = 0; m < 4; ++m)                                    \
            _Pragma("unroll")                                          \
            for (int n = 0; n < 4; ++n) {                              \
                acc[m][n] = __builtin_amdgcn_mfma_f32_16x16x32_bf16(afS[m][0], bfr[n][0], acc[m][n], 0, 0, 0); \
                acc[m][n] = __builtin_amdgcn_mfma_f32_16x16x32_bf16(afS[m][1], bfr[n][1], acc[m][n], 0, 0, 0); \
            }                                                          \
        __builtin_amdgcn_s_setprio(0);                                 \
    } while (0)

    bf16x8 af0[4][2], af1[4][2];
    f32x4 acc[4][4] = {};

    // prologue: A(0) -> af0, B(0) -> slot 0  (12 VMEM in flight)
    LOAD_A(af0);
    STAGE_B(0);

#pragma unroll
    for (int TT = 0; TT < 8; ++TT) {
        // ---- even window T = 2TT: compute af0 / slot T&1=0; load af1 ----
        if (TT > 0) {
            __builtin_amdgcn_s_barrier();   // slot-1 readers (T-1) done
            __builtin_amdgcn_sched_barrier(0);
        }
        {
            LOAD_A(af1);                    // A(T+1) -> af1
            STAGE_B(1);                     // B(T+1) -> slot 1
            __builtin_amdgcn_sched_barrier(0);
            asm volatile("s_waitcnt vmcnt(12)" ::: "memory");  // A(T),B(T) done
            __builtin_amdgcn_s_barrier();
            __builtin_amdgcn_sched_barrier(0);
            COMPUTE(af0, 0);
        }
        // ---- odd window T = 2TT+1: compute af1 / slot 1; load af0 ----
        {
            __builtin_amdgcn_s_barrier();   // slot-0 readers (even window) done
            __builtin_amdgcn_sched_barrier(0);
            if (TT < 7) {
                LOAD_A(af0);                // A(T+1) -> af0
                STAGE_B(0);                 // B(T+1) -> slot 0
                __builtin_amdgcn_sched_barrier(0);
                asm volatile("s_waitcnt vmcnt(12)" ::: "memory");
            } else {
                asm volatile("s_waitcnt vmcnt(0)" ::: "memory");
            }
            __builtin_amdgcn_s_barrier();
            __builtin_amdgcn_sched_barrier(0);
            COMPUTE(af1, 1);
        }
    }
#undef STAGE_B
#undef LOAD_A
#undef COMPUTE

    // fused QKV epilogue (R10): row = m0+wr*64+m*16+g*4+j, col = n0+wc*64+n*16+i15
    const int sec = n0 >> 10;        // 0=q, 1=k, 2=v (128-blocks never straddle)
    if (sec < 2) {
        const float qs = (sec == 0) ? QSCALE : 1.0f;
#pragma unroll
        for (int m = 0; m < 4; ++m) {
#pragma unroll
            for (int pp = 0; pp < 2; ++pp) {     // pairs (n=pp, n=pp+2): cols d, d+32
                int d = pp * 16 + i15;
                int collo = n0 + wc * 64 + pp * 16 + i15;
                float blo = bias[collo], bhi = bias[collo + 32];
#pragma unroll
                for (int j = 0; j < 4; ++j) {
                    int row = m0 + wr * 64 + m * 16 + g * 4 + j;
                    int l = row & 2047;
                    float2 cs = *(const float2*)&tab[(l * 32 + d) * 2];
                    float x1 = acc[m][pp][j] + blo;
                    float x2 = acc[m][pp + 2][j] + bhi;
                    out[(size_t)row * 3072 + collo]      = f2bf((x1 * cs.x - x2 * cs.y) * qs);
                    out[(size_t)row * 3072 + collo + 32] = f2bf((x2 * cs.x + x1 * cs.y) * qs);
                }
            }
        }
    } else {
        // v section: write V^T directly. VT[(b*16+h)*64 + d][l], 4 l per lane.
#pragma unroll
        for (int m = 0; m < 4; ++m) {
            int rbase = m0 + wr * 64 + m * 16 + g * 4;
            int lbase = rbase & 2047, bidx = rbase >> 11;
#pragma unroll
            for (int n = 0; n < 4; ++n) {
                int vcol = (n0 - 2048) + wc * 64 + n * 16 + i15;
                int h = vcol >> 6, d = vcol & 63;
                float bb = bias[n0 + wc * 64 + n * 16 + i15];
                union { unsigned w[2]; s16x4 v; } u;
                u.w[0] = cvtpk(acc[m][n][0] + bb, acc[m][n][1] + bb);
                u.w[1] = cvtpk(acc[m][n][2] + bb, acc[m][n][3] + bb);
                *(s16x4*)&VTout[((size_t)(bidx * 16 + h) * 64 + d) * 2048 + lbase] = u.v;
            }
        }
    }
}

// ---------------- out-proj GEMM (R10-exact): BK=64, A+B via 2-slot LDS ----
__global__ __launch_bounds__(256, 2)
void gemm_out(const short* __restrict__ A,
              const short* __restrict__ B,
              const float* __restrict__ bias,
              float* __restrict__ Cout,
              int M, int N, int K) {
    __shared__ short lds[2 * 16384];   // slot = A[128x64] + B[128x64] = 32 KB
    const int tid = threadIdx.x;
    const int lane = tid & 63, wave = tid >> 6;
    const int i15 = lane & 15, g = lane >> 4;
    const int wr = wave >> 1, wc = wave & 1;

    const int nbx = gridDim.x;
    const int nwg = nbx * gridDim.y;
    int bid = blockIdx.y * nbx + blockIdx.x;
    int sw = (bid & 7) * (nwg >> 3) + (bid >> 3);
    const int m0 = (sw / nbx) * 128;
    const int n0 = (sw % nbx) * 128;

    const int xr3 = i15 & 3, xb2 = (i15 >> 2) & 1;
    const int cLo = g ^ xr3;
    const int aoff0 = (wr * 64 + i15) * 64 + (xb2 * 4 + cLo) * 8;
    const int aoff1 = (wr * 64 + i15) * 64 + ((1 ^ xb2) * 4 + cLo) * 8;
    const int boff0 = (wc * 64 + i15) * 64 + (xb2 * 4 + cLo) * 8;
    const int boff1 = (wc * 64 + i15) * 64 + ((1 ^ xb2) * 4 + cLo) * 8;

    const int srow = tid >> 3;
    const int ss = (tid & 7) ^ (srow & 7);
    const short* a0 = A + (size_t)(m0 + srow) * K + ss * 8;
    const short* a1 = a0 + (size_t)32 * K;
    const short* a2 = a0 + (size_t)64 * K;
    const short* a3 = a0 + (size_t)96 * K;
    const short* b0 = B + (size_t)(n0 + srow) * K + ss * 8;
    const short* b1 = b0 + (size_t)32 * K;
    const short* b2 = b0 + (size_t)64 * K;
    const short* b3 = b0 + (size_t)96 * K;

#define STAGE(slot)                                                       \
    do {                                                                  \
        gld_lds16(a0, lds + (slot) * 16384 + 0 * 2048 + wave * 512);      \
        gld_lds16(a1, lds + (slot) * 16384 + 1 * 2048 + wave * 512);      \
        gld_lds16(a2, lds + (slot) * 16384 + 2 * 2048 + wave * 512);      \
        gld_lds16(a3, lds + (slot) * 16384 + 3 * 2048 + wave * 512);      \
        gld_lds16(b0, lds + (slot) * 16384 + 8192 + 0 * 2048 + wave * 512); \
        gld_lds16(b1, lds + (slot) * 16384 + 8192 + 1 * 2048 + wave * 512); \
        gld_lds16(b2, lds + (slot) * 16384 + 8192 + 2 * 2048 + wave * 512); \
        gld_lds16(b3, lds + (slot) * 16384 + 8192 + 3 * 2048 + wave * 512); \
        a0 += 64; a1 += 64; a2 += 64; a3 += 64;                           \
        b0 += 64; b1 += 64; b2 += 64; b3 += 64;                           \
    } while (0)

    STAGE(0);

    f32x4 acc[4][4] = {};
    const int NT = K >> 6;

    for (int T = 0; T < NT; ++T) {
        const int cur = T & 1;
        if (T > 0) {
            __builtin_amdgcn_s_barrier();
            __builtin_amdgcn_sched_barrier(0);
        }
        if (T + 1 < NT) {
            STAGE(cur ^ 1);
            asm volatile("s_waitcnt vmcnt(8)" ::: "memory");
        } else {
            asm volatile("s_waitcnt vmcnt(0)" ::: "memory");
        }
        __builtin_amdgcn_s_barrier();
        __builtin_amdgcn_sched_barrier(0);

        const short* As_ = lds + cur * 16384;
        const short* Bs_ = As_ + 8192;
        bf16x8 af[4][2], bfr[4][2];
#pragma unroll
        for (int m = 0; m < 4; ++m) {
            af[m][0] = *(const bf16x8*)&As_[aoff0 + m * 1024];
            af[m][1] = *(const bf16x8*)&As_[aoff1 + m * 1024];
        }
#pragma unroll
        for (int n = 0; n < 4; ++n) {
            bfr[n][0] = *(const bf16x8*)&Bs_[boff0 + n * 1024];
            bfr[n][1] = *(const bf16x8*)&Bs_[boff1 + n * 1024];
        }
        __builtin_amdgcn_s_setprio(1);
#pragma unroll
        for (int m = 0; m < 4; ++m)
#pragma unroll
            for (int n = 0; n < 4; ++n)
#pragma unroll
                for (int ks = 0; ks < 2; ++ks)
                    acc[m][n] = __builtin_amdgcn_mfma_f32_16x16x32_bf16(af[m][ks], bfr[n][ks], acc[m][n], 0, 0, 0);
        __builtin_amdgcn_s_setprio(0);
    }
#undef STAGE

#pragma unroll
    for (int m = 0; m < 4; ++m)
#pragma unroll
        for (int n = 0; n < 4; ++n) {
            int col = n0 + wc * 64 + n * 16 + i15;
            float bcol = bias[col];
#pragma unroll
            for (int j = 0; j < 4; ++j) {
                int row = m0 + wr * 64 + m * 16 + g * 4 + j;
                Cout[(size_t)row * N + col] = acc[m][n][j] + bcol;
            }
        }
}

// ---------------- flash attention: 32 q-rows per wave (R10-exact) --------
__global__ __launch_bounds__(256, 4) void attn_kernel(const short* __restrict__ qkv,
                                                      const short* __restrict__ VT,
                                                      short* __restrict__ O) {
    __shared__ short Ks[2][64 * 64];
    __shared__ short Vs[2][64 * 64];
    int orig = blockIdx.x;
    int xcd = orig & 7, idx = orig >> 3;        // idx in [0,128)
    int bh = xcd * 8 + (idx >> 4), qt = idx & 15;
    int b = bh >> 4, h = bh & 15;
    int tid = threadIdx.x, lane = tid & 63, wave = tid >> 6;
    int i15 = lane & 15, g = lane >> 4;
    int q0 = qt * 128;

    size_t qbase = (size_t)(b * 2048 + q0 + wave * 32);
    bf16x8 qf[2][2];
#pragma unroll
    for (int qg = 0; qg < 2; ++qg) {
        qf[qg][0] = *(const bf16x8*)&qkv[(qbase + qg * 16 + i15) * 3072 + h * 64 + 0  + g * 8];
        qf[qg][1] = *(const bf16x8*)&qkv[(qbase + qg * 16 + i15) * 3072 + h * 64 + 32 + g * 8];
    }

    bf16x8 onesf;
#pragma unroll
    for (int e = 0; e < 8; ++e) onesf[e] = (short)0x3F80;   // bf16 1.0

    const int srow = tid >> 3;
    const int ss8 = (tid & 7) ^ (srow & 7);
    const int pr0 = (srow & 0x23) | ((srow & 0x10) >> 2) | ((srow & 0x0C) << 1);
    const int sr1 = srow + 32;
    const int pr1 = (sr1 & 0x23) | ((sr1 & 0x10) >> 2) | ((sr1 & 0x0C) << 1);
    const short* kb_ = qkv + (size_t)(b * 2048) * 3072 + 1024 + h * 64 + ss8 * 8;
    const short* kp0 = kb_ + (size_t)pr0 * 3072;
    const short* kp1 = kb_ + (size_t)pr1 * 3072;
    const short* vb_ = VT + (size_t)bh * 64 * 2048 + ss8 * 8;
    const short* vp0 = vb_ + (size_t)srow * 2048;
    const short* vp1 = vb_ + (size_t)sr1 * 2048;

    const int xr3 = i15 & 3, xb2 = (i15 >> 2) & 1;
    const int cLo = g ^ xr3;
    const int o0 = i15 * 64 + (xb2 * 4 + cLo) * 8;
    const int o1 = i15 * 64 + ((1 ^ xb2) * 4 + cLo) * 8;

    f32x4 acc_o[2][4] = {};
    f32x4 acc_l[2] = {};

#define STAGE(bk, bv)                                        \
    do {                                                     \
        gld_lds16(kp0, (bk) + wave * 512);                   \
        gld_lds16(kp1, (bk) + 2048 + wave * 512);            \
        gld_lds16(vp0, (bv) + wave * 512);                   \
        gld_lds16(vp1, (bv) + 2048 + wave * 512);            \
        kp0 += (size_t)64 * 3072; kp1 += (size_t)64 * 3072;  \
        vp0 += 64; vp1 += 64;                                \
    } while (0)

    STAGE(Ks[0], Vs[0]);

    for (int t = 0; t < 32; ++t) {
        const int cur = t & 1;
        if (t > 0) {
            __builtin_amdgcn_s_barrier();
            __builtin_amdgcn_sched_barrier(0);
        }
        if (t + 1 < 32) {
            STAGE(Ks[cur ^ 1], Vs[cur ^ 1]);
            asm volatile("s_waitcnt vmcnt(4)" ::: "memory");
        } else {
            asm volatile("s_waitcnt vmcnt(0)" ::: "memory");
        }
        __builtin_amdgcn_s_barrier();
        __builtin_amdgcn_sched_barrier(0);

        const short* ks = Ks[cur];
        const short* vs = Vs[cur];

        f32x4 sa[2][4] = {};
        __builtin_amdgcn_s_setprio(1);
#pragma unroll
        for (int kb = 0; kb < 2; ++kb) {
            const int ko = kb ? o1 : o0;
            bf16x8 kf[4];
#pragma unroll
            for (int jb = 0; jb < 4; ++jb) kf[jb] = *(const bf16x8*)&ks[ko + jb * 1024];
#pragma unroll
            for (int qg = 0; qg < 2; ++qg)
#pragma unroll
                for (int jb = 0; jb < 4; ++jb)
                    sa[qg][jb] = __builtin_amdgcn_mfma_f32_16x16x32_bf16(kf[jb], qf[qg][kb], sa[qg][jb], 0, 0, 0);
        }
        __builtin_amdgcn_s_setprio(0);

        bf16x8 pf[2][2];
#pragma unroll
        for (int qg = 0; qg < 2; ++qg) {
            float p[4][4];
#pragma unroll
            for (int jb = 0; jb < 4; ++jb)
#pragma unroll
                for (int r = 0; r < 4; ++r)
                    p[jb][r] = __builtin_amdgcn_exp2f(sa[qg][jb][r]);
#pragma unroll
            for (int kb = 0; kb < 2; ++kb) {
                union { unsigned w[4]; bf16x8 v; } u;
                u.w[0] = cvtpk(p[2 * kb][0],     p[2 * kb][1]);
                u.w[1] = cvtpk(p[2 * kb][2],     p[2 * kb][3]);
                u.w[2] = cvtpk(p[2 * kb + 1][0], p[2 * kb + 1][1]);
                u.w[3] = cvtpk(p[2 * kb + 1][2], p[2 * kb + 1][3]);
                pf[qg][kb] = u.v;
            }
        }

        __builtin_amdgcn_s_setprio(1);
#pragma unroll
        for (int db = 0; db < 4; ++db) {
#pragma unroll
            for (int kb = 0; kb < 2; ++kb) {
                bf16x8 vf = *(const bf16x8*)&vs[(kb ? o1 : o0) + db * 1024];
#pragma unroll
                for (int qg = 0; qg < 2; ++qg)
                    acc_o[qg][db] = __builtin_amdgcn_mfma_f32_16x16x32_bf16(pf[qg][kb], vf, acc_o[qg][db], 0, 0, 0);
            }
        }
#pragma unroll
        for (int qg = 0; qg < 2; ++qg) {
            acc_l[qg] = __builtin_amdgcn_mfma_f32_16x16x32_bf16(pf[qg][0], onesf, acc_l[qg], 0, 0, 0);
            acc_l[qg] = __builtin_amdgcn_mfma_f32_16x16x32_bf16(pf[qg][1], onesf, acc_l[qg], 0, 0, 0);
        }
        __builtin_amdgcn_s_setprio(0);
    }
#undef STAGE

#pragma unroll
    for (int qg = 0; qg < 2; ++qg) {
        float linv4[4];
#pragma unroll
        for (int r = 0; r < 4; ++r) linv4[r] = 1.f / acc_l[qg][r];
#pragma unroll
        for (int db = 0; db < 4; ++db) {
            int ocol = h * 64 + db * 16 + i15;
#pragma unroll
            for (int r = 0; r < 4; ++r) {
                size_t orow = qbase + qg * 16 + g * 4 + r;
                O[orow * 1024 + ocol] = f2bf(acc_o[qg][db][r] * linv4[r]);
            }
        }
    }
}

extern "C" void kernel_launch(void* const* d_in, const int* in_sizes, int n_in,
                              void* d_out, int out_size, void* d_ws, size_t ws_size,
                              hipStream_t stream) {
    const float* x     = (const float*)d_in[0];
    const float* w_qkv = (const float*)d_in[1];
    const float* b_qkv = (const float*)d_in[2];
    const float* w_out = (const float*)d_in[3];
    const float* b_out = (const float*)d_in[4];

    char* ws = (char*)d_ws;
    short* qkvb = (short*)(ws);                 // 8192*3072*2  = 50331648 (v sec unused)
    short* xp   = (short*)(ws + 50331648);      // 8192*1024*2  = 16777216 (packed x; reused as O)
    short* wqb  = (short*)(ws + 67108864);      // 3072*1024*2  =  6291456
    short* wob  = (short*)(ws + 73400320);      // 1024*1024*2  =  2097152
    short* VT   = (short*)(ws + 75497472);      // 64*64*2048*2 = 16777216
    float* rt   = (float*)(ws + 92274688);      // 2048*32*2*4  =   524288
    short* Ob   = xp;                           // attn output overwrites packed x (post-QKV)

    prep_kernel<<<6400, 256, 0, stream>>>(x, w_qkv, w_out, xp, wqb, wob, rt);

    gemm_qkv<<<dim3(24, 64), 256, 0, stream>>>(xp, wqb, b_qkv, qkvb, VT, rt);
    attn_kernel<<<1024, 256, 0, stream>>>(qkvb, VT, Ob);
    gemm_out<<<dim3(8, 64), 256, 0, stream>>>(Ob, wob, b_out, (float*)d_out, 8192, 1024, 1024);
}

// Round 18
// 162.320 us; speedup vs baseline: 2.4641x; 1.0678x over previous
//
#include <hip/hip_runtime.h>
#include <stdint.h>

typedef __attribute__((ext_vector_type(4))) float f32x4;
typedef __attribute__((ext_vector_type(8))) short bf16x8;
typedef __attribute__((ext_vector_type(4))) short s16x4;
typedef __attribute__((ext_vector_type(4))) float fp32x4;

#define QSCALE 0.18033688f   // 0.125 * log2(e): scores exit QK^T in log2 domain

__device__ __forceinline__ short f2bf(float f) {
    union { float f; unsigned u; } v; v.f = f;
    unsigned u = v.u;
    unsigned r = u + 0x7fffu + ((u >> 16) & 1u);
    return (short)(r >> 16);
}
// packed bf16 convert (RNE), lo = a, hi = b
__device__ __forceinline__ unsigned cvtpk(float a, float b) {
    unsigned r;
    asm("v_cvt_pk_bf16_f32 %0, %1, %2" : "=v"(r) : "v"(a), "v"(b));
    return r;
}

// async global->LDS, 16B per lane. dest = wave-uniform base + lane*16.
__device__ __forceinline__ void gld_lds16(const void* g, void* l) {
    __builtin_amdgcn_global_load_lds(
        (const __attribute__((address_space(1))) unsigned int*)(uintptr_t)g,
        (__attribute__((address_space(3))) unsigned int*)(uintptr_t)l,
        16, 0, 0);
}

// ---------------- fused prep: all casts + RoPE table in ONE launch --------
__global__ __launch_bounds__(256) void prep_kernel(const float* __restrict__ x,
                                                   const float* __restrict__ wq,
                                                   const float* __restrict__ wo,
                                                   short* __restrict__ xb,
                                                   short* __restrict__ wqb,
                                                   short* __restrict__ wob,
                                                   float* __restrict__ tab) {
    int bid = blockIdx.x, tid = threadIdx.x;
    if (bid < 6144) {
        const float* in; short* out; int base;
        if (bid < 4096)      { in = x;  out = xb;  base = bid; }
        else if (bid < 5632) { in = wq; out = wqb; base = bid - 4096; }
        else                 { in = wo; out = wob; base = bid - 5632; }
        int idx = (base * 256 + tid) * 8;
        fp32x4 a = *(const fp32x4*)&in[idx];
        fp32x4 b = *(const fp32x4*)&in[idx + 4];
        union { unsigned w[4]; bf16x8 v; } u;
        u.w[0] = cvtpk(a[0], a[1]); u.w[1] = cvtpk(a[2], a[3]);
        u.w[2] = cvtpk(b[0], b[1]); u.w[3] = cvtpk(b[2], b[3]);
        *(bf16x8*)&out[idx] = u.v;
    } else {
        int idx = (bid - 6144) * 256 + tid;   // 65536
        int l = idx >> 5, d = idx & 31;
        float inv = expf(-(float)d / 32.f * logf(10000.f));
        float ang = (float)l * inv;
        tab[idx * 2 + 0] = cosf(ang);
        tab[idx * 2 + 1] = sinf(ang);
    }
}

// ---------------- GEMM: C[M,N] = A[M,K]*B[N,K]^T + bias, bf16 in ----------
// BM=BN=128, BK=64, 4 waves (2x2), per-wave 64x64 output, 256 threads.
// 2-slot LDS ring = 64 KB -> 2 blocks/CU co-resident: when one block sits at
// its barrier/vmcnt, the other's waves keep the MFMA pipe fed (m97/m114
// mechanism). Window: {barrier; STAGE(T+1) 8 loads; vmcnt(8) [T landed,
// T+1 in flight]; barrier; ds_read 16 frags + 32 MFMA (setprio)}.
// Grids: QKV 24x64=1536 (3 exact rounds), out-proj 8x64=512 (1 round).
// MODE 0: fp32 out + bias. MODE 1: fused QKV epilogue (RoPE q/k, +QSCALE on
// q, bf16 qkv; v section written transposed to VT[bh][d][L]).
template<int MODE>
__global__ __launch_bounds__(256, 2)
void gemm_bt(const short* __restrict__ A,
             const short* __restrict__ B,
             const float* __restrict__ bias,
             void* __restrict__ Cout,
             short* __restrict__ VTout,
             const float* __restrict__ tab,
             int M, int N, int K) {
    __shared__ short lds[2 * 16384];   // slot = A[128x64] (16 KB) + B[128x64] (16 KB)
    const int tid = threadIdx.x;
    const int lane = tid & 63, wave = tid >> 6;
    const int i15 = lane & 15, g = lane >> 4;
    const int wr = wave >> 1, wc = wave & 1;

    // bijective XCD chunk-swizzle (nwg % 8 == 0 for all our grids)
    const int nbx = gridDim.x;
    const int nwg = nbx * gridDim.y;
    int bid = blockIdx.y * nbx + blockIdx.x;
    int sw = (bid & 7) * (nwg >> 3) + (bid >> 3);
    const int m0 = (sw / nbx) * 128;
    const int n0 = (sw % nbx) * 128;

    // per-lane LDS read bases: swizzled col = (ks*4+g) ^ (i15&7); split XOR into
    // low2 (g^xr3) and bit2 (ks^xb2) so each ks gets base + imm-offset reads.
    const int xr3 = i15 & 3, xb2 = (i15 >> 2) & 1;
    const int cLo = g ^ xr3;
    const int aoff0 = (wr * 64 + i15) * 64 + (xb2 * 4 + cLo) * 8;
    const int aoff1 = (wr * 64 + i15) * 64 + ((1 ^ xb2) * 4 + cLo) * 8;
    const int boff0 = (wc * 64 + i15) * 64 + (xb2 * 4 + cLo) * 8;
    const int boff1 = (wc * 64 + i15) * 64 + ((1 ^ xb2) * 4 + cLo) * 8;

    // staging: thread covers rows r*32 + (tid>>3), col-group tid&7, r in 0..3.
    // (r*32+srow)&7 == srow&7 -> one pre-swizzled col per thread.
    const int srow = tid >> 3;
    const int ss = (tid & 7) ^ (srow & 7);
    const short* a0 = A + (size_t)(m0 + srow) * K + ss * 8;
    const short* a1 = a0 + (size_t)32 * K;
    const short* a2 = a0 + (size_t)64 * K;
    const short* a3 = a0 + (size_t)96 * K;
    const short* b0 = B + (size_t)(n0 + srow) * K + ss * 8;
    const short* b1 = b0 + (size_t)32 * K;
    const short* b2 = b0 + (size_t)64 * K;
    const short* b3 = b0 + (size_t)96 * K;

    // dest: A r-chunk at slot*16384 + r*2048 + wave*512 (+ lane*16B); B at +8192
#define STAGE(slot)                                                       \
    do {                                                                  \
        gld_lds16(a0, lds + (slot) * 16384 + 0 * 2048 + wave * 512);      \
        gld_lds16(a1, lds + (slot) * 16384 + 1 * 2048 + wave * 512);      \
        gld_lds16(a2, lds + (slot) * 16384 + 2 * 2048 + wave * 512);      \
        gld_lds16(a3, lds + (slot) * 16384 + 3 * 2048 + wave * 512);      \
        gld_lds16(b0, lds + (slot) * 16384 + 8192 + 0 * 2048 + wave * 512); \
        gld_lds16(b1, lds + (slot) * 16384 + 8192 + 1 * 2048 + wave * 512); \
        gld_lds16(b2, lds + (slot) * 16384 + 8192 + 2 * 2048 + wave * 512); \
        gld_lds16(b3, lds + (slot) * 16384 + 8192 + 3 * 2048 + wave * 512); \
        a0 += 64; a1 += 64; a2 += 64; a3 += 64;                           \
        b0 += 64; b1 += 64; b2 += 64; b3 += 64;                           \
    } while (0)

    STAGE(0);

    f32x4 acc[4][4] = {};
    const int NT = K >> 6;

    for (int T = 0; T < NT; ++T) {
        const int cur = T & 1;
        if (T > 0) {
            __builtin_amdgcn_s_barrier();          // all waves done reading slot cur
            __builtin_amdgcn_sched_barrier(0);
        }
        if (T + 1 < NT) {
            STAGE(cur ^ 1);                        // 8 loads for tile T+1
            asm volatile("s_waitcnt vmcnt(8)" ::: "memory");  // tile T landed
        } else {
            asm volatile("s_waitcnt vmcnt(0)" ::: "memory");
        }
        __builtin_amdgcn_s_barrier();
        __builtin_amdgcn_sched_barrier(0);

        const short* As_ = lds + cur * 16384;
        const short* Bs_ = As_ + 8192;
        bf16x8 af[4][2], bfr[4][2];
#pragma unroll
        for (int m = 0; m < 4; ++m) {
            af[m][0] = *(const bf16x8*)&As_[aoff0 + m * 1024];
            af[m][1] = *(const bf16x8*)&As_[aoff1 + m * 1024];
        }
#pragma unroll
        for (int n = 0; n < 4; ++n) {
            bfr[n][0] = *(const bf16x8*)&Bs_[boff0 + n * 1024];
            bfr[n][1] = *(const bf16x8*)&Bs_[boff1 + n * 1024];
        }
        __builtin_amdgcn_s_setprio(1);
#pragma unroll
        for (int m = 0; m < 4; ++m)
#pragma unroll
            for (int n = 0; n < 4; ++n)
#pragma unroll
                for (int ks = 0; ks < 2; ++ks)
                    acc[m][n] = __builtin_amdgcn_mfma_f32_16x16x32_bf16(af[m][ks], bfr[n][ks], acc[m][n], 0, 0, 0);
        __builtin_amdgcn_s_setprio(0);
    }
#undef STAGE

    // epilogue: C row = m0+wr*64+m*16+g*4+j, col = n0+wc*64+n*16+i15
    if (MODE == 0) {
#pragma unroll
        for (int m = 0; m < 4; ++m)
#pragma unroll
            for (int n = 0; n < 4; ++n) {
                int col = n0 + wc * 64 + n * 16 + i15;
                float bcol = bias[col];
#pragma unroll
                for (int j = 0; j < 4; ++j) {
                    int row = m0 + wr * 64 + m * 16 + g * 4 + j;
                    ((float*)Cout)[(size_t)row * N + col] = acc[m][n][j] + bcol;
                }
            }
    } else {
        const int sec = n0 >> 10;        // 0=q, 1=k, 2=v (128-blocks never straddle)
        if (sec < 2) {
            const float qs = (sec == 0) ? QSCALE : 1.0f;
            short* out = (short*)Cout;
#pragma unroll
            for (int m = 0; m < 4; ++m) {
#pragma unroll
                for (int pp = 0; pp < 2; ++pp) {     // pairs (n=pp, n=pp+2): cols d, d+32
                    int d = pp * 16 + i15;
                    int collo = n0 + wc * 64 + pp * 16 + i15;
                    float blo = bias[collo], bhi = bias[collo + 32];
#pragma unroll
                    for (int j = 0; j < 4; ++j) {
                        int row = m0 + wr * 64 + m * 16 + g * 4 + j;
                        int l = row & 2047;
                        float2 cs = *(const float2*)&tab[(l * 32 + d) * 2];
                        float x1 = acc[m][pp][j] + blo;
                        float x2 = acc[m][pp + 2][j] + bhi;
                        out[(size_t)row * 3072 + collo]      = f2bf((x1 * cs.x - x2 * cs.y) * qs);
                        out[(size_t)row * 3072 + collo + 32] = f2bf((x2 * cs.x + x1 * cs.y) * qs);
                    }
                }
            }
        } else {
            // v section: write V^T directly. VT[(b*16+h)*64 + d][l], 4 l per lane.
#pragma unroll
            for (int m = 0; m < 4; ++m) {
                int rbase = m0 + wr * 64 + m * 16 + g * 4;
                int lbase = rbase & 2047, bidx = rbase >> 11;
#pragma unroll
                for (int n = 0; n < 4; ++n) {
                    int vcol = (n0 - 2048) + wc * 64 + n * 16 + i15;
                    int h = vcol >> 6, d = vcol & 63;
                    float bb = bias[n0 + wc * 64 + n * 16 + i15];
                    union { unsigned w[2]; s16x4 v; } u;
                    u.w[0] = cvtpk(acc[m][n][0] + bb, acc[m][n][1] + bb);
                    u.w[1] = cvtpk(acc[m][n][2] + bb, acc[m][n][3] + bb);
                    *(s16x4*)&VTout[((size_t)(bidx * 16 + h) * 64 + d) * 2048 + lbase] = u.v;
                }
            }
        }
    }
}

// ---------------- flash attention: 32 q-rows per wave --------------------
// 4 waves x 32 q-rows = 128 q-rows/block, 256 threads; KV tiles of 64,
// double-buffered (32 KB). Each wave reads the K/V fragments ONCE per tile
// and feeds TWO Q-groups -> LDS-read traffic per q-row halved. S^T = K*Q^T
// with permuted K rows (QK^T output registers ARE the PV A-fragment);
// p = exp2(s) direct; l via ones-MFMA. Grid 1024 = 4 blk/CU, XCD-swizzled.
__global__ __launch_bounds__(256, 4) void attn_kernel(const short* __restrict__ qkv,
                                                      const short* __restrict__ VT,
                                                      short* __restrict__ O) {
    __shared__ short Ks[2][64 * 64];
    __shared__ short Vs[2][64 * 64];
    int orig = blockIdx.x;
    int xcd = orig & 7, idx = orig >> 3;        // idx in [0,128)
    int bh = xcd * 8 + (idx >> 4), qt = idx & 15;
    int b = bh >> 4, h = bh & 15;
    int tid = threadIdx.x, lane = tid & 63, wave = tid >> 6;
    int i15 = lane & 15, g = lane >> 4;
    int q0 = qt * 128;

    size_t qbase = (size_t)(b * 2048 + q0 + wave * 32);
    bf16x8 qf[2][2];
#pragma unroll
    for (int qg = 0; qg < 2; ++qg) {
        qf[qg][0] = *(const bf16x8*)&qkv[(qbase + qg * 16 + i15) * 3072 + h * 64 + 0  + g * 8];
        qf[qg][1] = *(const bf16x8*)&qkv[(qbase + qg * 16 + i15) * 3072 + h * 64 + 32 + g * 8];
    }

    bf16x8 onesf;
#pragma unroll
    for (int e = 0; e < 8; ++e) onesf[e] = (short)0x3F80;   // bf16 1.0

    const int srow = tid >> 3;
    const int ss8 = (tid & 7) ^ (srow & 7);
    const int pr0 = (srow & 0x23) | ((srow & 0x10) >> 2) | ((srow & 0x0C) << 1);
    const int sr1 = srow + 32;
    const int pr1 = (sr1 & 0x23) | ((sr1 & 0x10) >> 2) | ((sr1 & 0x0C) << 1);
    const short* kb_ = qkv + (size_t)(b * 2048) * 3072 + 1024 + h * 64 + ss8 * 8;
    const short* kp0 = kb_ + (size_t)pr0 * 3072;
    const short* kp1 = kb_ + (size_t)pr1 * 3072;
    const short* vb_ = VT + (size_t)bh * 64 * 2048 + ss8 * 8;
    const short* vp0 = vb_ + (size_t)srow * 2048;
    const short* vp1 = vb_ + (size_t)sr1 * 2048;

    const int xr3 = i15 & 3, xb2 = (i15 >> 2) & 1;
    const int cLo = g ^ xr3;
    const int o0 = i15 * 64 + (xb2 * 4 + cLo) * 8;
    const int o1 = i15 * 64 + ((1 ^ xb2) * 4 + cLo) * 8;

    f32x4 acc_o[2][4] = {};
    f32x4 acc_l[2] = {};

#define STAGE(bk, bv)                                        \
    do {                                                     \
        gld_lds16(kp0, (bk) + wave * 512);                   \
        gld_lds16(kp1, (bk) + 2048 + wave * 512);            \
        gld_lds16(vp0, (bv) + wave * 512);                   \
        gld_lds16(vp1, (bv) + 2048 + wave * 512);            \
        kp0 += (size_t)64 * 3072; kp1 += (size_t)64 * 3072;  \
        vp0 += 64; vp1 += 64;                                \
    } while (0)

    STAGE(Ks[0], Vs[0]);

    for (int t = 0; t < 32; ++t) {
        const int cur = t & 1;
        if (t > 0) {
            __builtin_amdgcn_s_barrier();
            __builtin_amdgcn_sched_barrier(0);
        }
        if (t + 1 < 32) {
            STAGE(Ks[cur ^ 1], Vs[cur ^ 1]);
            asm volatile("s_waitcnt vmcnt(4)" ::: "memory");
        } else {
            asm volatile("s_waitcnt vmcnt(0)" ::: "memory");
        }
        __builtin_amdgcn_s_barrier();
        __builtin_amdgcn_sched_barrier(0);

        const short* ks = Ks[cur];
        const short* vs = Vs[cur];

        f32x4 sa[2][4] = {};
        __builtin_amdgcn_s_setprio(1);
#pragma unroll
        for (int kb = 0; kb < 2; ++kb) {
            const int ko = kb ? o1 : o0;
            bf16x8 kf[4];
#pragma unroll
            for (int jb = 0; jb < 4; ++jb) kf[jb] = *(const bf16x8*)&ks[ko + jb * 1024];
#pragma unroll
            for (int qg = 0; qg < 2; ++qg)
#pragma unroll
                for (int jb = 0; jb < 4; ++jb)
                    sa[qg][jb] = __builtin_amdgcn_mfma_f32_16x16x32_bf16(kf[jb], qf[qg][kb], sa[qg][jb], 0, 0, 0);
        }
        __builtin_amdgcn_s_setprio(0);

        bf16x8 pf[2][2];
#pragma unroll
        for (int qg = 0; qg < 2; ++qg) {
            float p[4][4];
#pragma unroll
            for (int jb = 0; jb < 4; ++jb)
#pragma unroll
                for (int r = 0; r < 4; ++r)
                    p[jb][r] = __builtin_amdgcn_exp2f(sa[qg][jb][r]);
#pragma unroll
            for (int kb = 0; kb < 2; ++kb) {
                union { unsigned w[4]; bf16x8 v; } u;
                u.w[0] = cvtpk(p[2 * kb][0],     p[2 * kb][1]);
                u.w[1] = cvtpk(p[2 * kb][2],     p[2 * kb][3]);
                u.w[2] = cvtpk(p[2 * kb + 1][0], p[2 * kb + 1][1]);
                u.w[3] = cvtpk(p[2 * kb + 1][2], p[2 * kb + 1][3]);
                pf[qg][kb] = u.v;
            }
        }

        __builtin_amdgcn_s_setprio(1);
#pragma unroll
        for (int db = 0; db < 4; ++db) {
#pragma unroll
            for (int kb = 0; kb < 2; ++kb) {
                bf16x8 vf = *(const bf16x8*)&vs[(kb ? o1 : o0) + db * 1024];
#pragma unroll
                for (int qg = 0; qg < 2; ++qg)
                    acc_o[qg][db] = __builtin_amdgcn_mfma_f32_16x16x32_bf16(pf[qg][kb], vf, acc_o[qg][db], 0, 0, 0);
            }
        }
#pragma unroll
        for (int qg = 0; qg < 2; ++qg) {
            acc_l[qg] = __builtin_amdgcn_mfma_f32_16x16x32_bf16(pf[qg][0], onesf, acc_l[qg], 0, 0, 0);
            acc_l[qg] = __builtin_amdgcn_mfma_f32_16x16x32_bf16(pf[qg][1], onesf, acc_l[qg], 0, 0, 0);
        }
        __builtin_amdgcn_s_setprio(0);
    }
#undef STAGE

#pragma unroll
    for (int qg = 0; qg < 2; ++qg) {
        float linv4[4];
#pragma unroll
        for (int r = 0; r < 4; ++r) linv4[r] = 1.f / acc_l[qg][r];
#pragma unroll
        for (int db = 0; db < 4; ++db) {
            int ocol = h * 64 + db * 16 + i15;
#pragma unroll
            for (int r = 0; r < 4; ++r) {
                size_t orow = qbase + qg * 16 + g * 4 + r;
                O[orow * 1024 + ocol] = f2bf(acc_o[qg][db][r] * linv4[r]);
            }
        }
    }
}

extern "C" void kernel_launch(void* const* d_in, const int* in_sizes, int n_in,
                              void* d_out, int out_size, void* d_ws, size_t ws_size,
                              hipStream_t stream) {
    const float* x     = (const float*)d_in[0];
    const float* w_qkv = (const float*)d_in[1];
    const float* b_qkv = (const float*)d_in[2];
    const float* w_out = (const float*)d_in[3];
    const float* b_out = (const float*)d_in[4];

    char* ws = (char*)d_ws;
    short* qkvb = (short*)(ws);                 // 8192*3072*2  = 50331648 (v sec unused)
    short* xb   = (short*)(ws + 50331648);      // 8192*1024*2  = 16777216 (reused as O)
    short* wqb  = (short*)(ws + 67108864);      // 3072*1024*2  =  6291456
    short* wob  = (short*)(ws + 73400320);      // 1024*1024*2  =  2097152
    short* VT   = (short*)(ws + 75497472);      // 64*64*2048*2 = 16777216
    float* rt   = (float*)(ws + 92274688);      // 2048*32*2*4  =   524288
    short* Ob   = xb;                           // reuse x_bf16 region for attn output

    prep_kernel<<<6400, 256, 0, stream>>>(x, w_qkv, w_out, xb, wqb, wob, rt);

    gemm_bt<1><<<dim3(24, 64), 256, 0, stream>>>(xb, wqb, b_qkv, qkvb, VT, rt, 8192, 3072, 1024);
    attn_kernel<<<1024, 256, 0, stream>>>(qkvb, VT, Ob);
    gemm_bt<0><<<dim3(8, 64), 256, 0, stream>>>(Ob, wob, b_out, d_out, nullptr, nullptr, 8192, 1024, 1024);
}